// Round 5
// baseline (1037.242 us; speedup 1.0000x reference)
//
#include <hip/hip_runtime.h>

#define CDIM 384
#define FDIM 1536
#define KK 51
#define RAD 25
#define NPIX 32768     // B*H*W
#define HW 4096        // 64*64

typedef float  f32x4  __attribute__((ext_vector_type(4)));
typedef short  short8 __attribute__((ext_vector_type(8)));
typedef __bf16 bf16x8 __attribute__((ext_vector_type(8)));

// per-axis peripheral index: coords {0,1,2,4,8,16,25}, signed list P=13
__device__ __constant__ int AXIS[51] = {
  0,
  1,1,1,1,1,1,1,1,1,
  2,2,2,2,2,2,2,2,
  3,3,3,3,
  4,4,
  5,
  6,
  7,
  8,8,
  9,9,9,9,
  10,10,10,10,10,10,10,10,
  11,11,11,11,11,11,11,11,11,
  12
};

__device__ __forceinline__ unsigned short bf16_rn(float x){
  union { float f; unsigned u; } v; v.f = x;
  unsigned r = v.u + 0x7FFFu + ((v.u >> 16) & 1u);
  return (unsigned short)(r >> 16);
}
__device__ __forceinline__ float bf2f(unsigned short h){
  union { unsigned u; float f; } v; v.u = ((unsigned)h) << 16; return v.f;
}

// ---------------- K0: expand per-channel kernel: w[c,i,j] = wc[c, cell(i,j)] + kpe[i,j]
__global__ __launch_bounds__(256) void k_build_w(const float* __restrict__ wc,
                                                 const float* __restrict__ kpe,
                                                 float* __restrict__ wfull){
  int c = blockIdx.x;
  const float* wcc = wc + c*169;
  float* wo = wfull + (size_t)c*2601;
  for (int idx = threadIdx.x; idx < 2601; idx += 256){
    int i = idx / 51, j = idx - i*51;
    wo[idx] = wcc[AXIS[i]*13 + AXIS[j]] + kpe[idx];
  }
}

// ---------------- K1: depthwise conv 51x51, zero pad 25. One block = one (b,c), 32-row strip.
__global__ __launch_bounds__(256) void k_conv(const float* __restrict__ x,
                                              const float* __restrict__ wfull,
                                              float* __restrict__ y){
  __shared__ float xs[82*116];           // rows p0-25..p0+56, cols -25..90 (stride 116 for 16B align)
  int bid = blockIdx.x;
  int img = bid >> 1;                    // b*384 + c
  int p0  = (bid & 1) << 5;
  int ch  = img % CDIM;
  const float* xim = x + (size_t)img*HW;
  for (int idx = threadIdx.x; idx < 82*116; idx += 256){
    int rr = idx / 116;
    int cc = idx - rr*116;
    int rg = p0 + rr - RAD;
    int cg = cc - RAD;
    float v = 0.f;
    if (rg >= 0 && rg < 64 && cg >= 0 && cg < 64) v = xim[rg*64 + cg];
    xs[idx] = v;
  }
  __syncthreads();
  int t  = threadIdx.x;
  int q0 = (t & 7) << 3;                 // 8 consecutive output cols per thread
  int pr = t >> 3;                       // output row within strip [0,32)
  const float* wch = wfull + (size_t)ch*2601;
  float acc[8];
  #pragma unroll
  for (int m = 0; m < 8; ++m) acc[m] = 0.f;
  #pragma unroll 1
  for (int i = 0; i < KK; ++i){
    const float* xr = &xs[(pr + i)*116 + q0];
    f32x4 X[15];                         // window q0 .. q0+59
    #pragma unroll
    for (int k = 0; k < 15; ++k) X[k] = *(const f32x4*)(xr + 4*k);
    const float* wr = wch + i*51;        // wave-uniform -> scalar loads
    #pragma unroll
    for (int j = 0; j < KK; ++j){
      float w = wr[j];
      #pragma unroll
      for (int m = 0; m < 8; ++m){
        int u = j + m;
        acc[m] += w * X[u >> 2][u & 3];
      }
    }
  }
  float* yo = y + (size_t)img*HW + (p0 + pr)*64 + q0;
  f32x4 o0 = {acc[0],acc[1],acc[2],acc[3]};
  f32x4 o1 = {acc[4],acc[5],acc[6],acc[7]};
  *(f32x4*)yo = o0;
  *(f32x4*)(yo+4) = o1;
}

// ---------------- K2: LayerNorm over C (NCHW f32 -> NHWC bf16), LDS transpose for coalesced writes
__global__ __launch_bounds__(256) void k_ln(const float* __restrict__ y,
                                            const float* __restrict__ lnw,
                                            const float* __restrict__ lnb,
                                            unsigned short* __restrict__ yn){
  __shared__ unsigned short tile[4][64*66];
  int tid = threadIdx.x, lane = tid & 63, wid = tid >> 6;
  int pg = blockIdx.x*256 + wid*64 + lane;        // pixel id
  int b = pg >> 12, sp = pg & 4095;
  const float* yb = y + (size_t)b*CDIM*HW + sp;
  float sum = 0.f, sq = 0.f;
  for (int c = 0; c < CDIM; ++c){
    float v = yb[(size_t)c*HW];
    sum += v; sq += v*v;
  }
  float mu   = sum * (1.f/CDIM);
  float var  = sq  * (1.f/CDIM) - mu*mu;
  float rstd = rsqrtf(var + 1e-6f);
  unsigned short* tl = tile[wid];
  int pixbase = blockIdx.x*256 + wid*64;
  for (int c0 = 0; c0 < CDIM; c0 += 64){
    #pragma unroll 4
    for (int cc = 0; cc < 64; ++cc){
      int c = c0 + cc;
      float v = (yb[(size_t)c*HW] - mu) * rstd * lnw[c] + lnb[c];
      tl[cc*66 + lane] = bf16_rn(v);
    }
    // same-wave LDS RAW: compiler inserts waitcnt
    for (int p = 0; p < 64; ++p){
      yn[(size_t)(pixbase + p)*CDIM + c0 + lane] = tl[lane*66 + p];
    }
  }
}

// ---------------- K4/K5: weight transposes to bf16
__global__ __launch_bounds__(256) void k_w1t(const float* __restrict__ w1, unsigned short* __restrict__ w1T){
  int idx = blockIdx.x*256 + threadIdx.x;
  if (idx < CDIM*FDIM){ int c = idx / FDIM, f = idx - c*FDIM; w1T[(size_t)f*CDIM + c] = bf16_rn(w1[idx]); }
}
__global__ __launch_bounds__(256) void k_w2t(const float* __restrict__ w2, unsigned short* __restrict__ w2T){
  int idx = blockIdx.x*256 + threadIdx.x;
  if (idx < CDIM*FDIM){ int f = idx / CDIM, c = idx - f*CDIM; w2T[(size_t)c*FDIM + f] = bf16_rn(w2[idx]); }
}

// ---------------- K8: c2[c] = b2[c] + sum_f beta[f]*w2[f,c]
__global__ __launch_bounds__(128) void k_c2(const float* __restrict__ w2,
                                            const float* __restrict__ beta,
                                            const float* __restrict__ b2,
                                            float* __restrict__ c2){
  int c = blockIdx.x*128 + threadIdx.x;
  if (c < CDIM){
    float s = b2[c];
    for (int f = 0; f < FDIM; ++f) s += beta[f] * w2[(size_t)f*CDIM + c];
    c2[c] = s;
  }
}

// ---------------- K6: GEMM1 (M x 384) x (384 x 1536) + b1 + exact GELU -> H bf16; GRN partial sums
__global__ __launch_bounds__(256) void k_gemm1(const unsigned short* __restrict__ A,   // yn M x 384
                                               const unsigned short* __restrict__ BT,  // w1T 1536 x 384
                                               const float* __restrict__ b1,
                                               unsigned short* __restrict__ H,         // M x 1536
                                               float* __restrict__ grn){               // 8 x 1536
  __shared__ __align__(16) unsigned short aS[128*40];
  __shared__ __align__(16) unsigned short bS[128*40];
  int bid = blockIdx.x;
  int bm = bid & 255, bn = bid >> 8;
  int m0 = bm*128, n0 = bn*128;
  int tid = threadIdx.x;
  int lane = tid & 63, wid = tid >> 6;
  int wr = wid >> 1, wc = wid & 1;
  int lm = lane & 15, g = lane >> 4;
  int sr = tid & 127, sc = tid >> 7;
  f32x4 acc[4][4];
  #pragma unroll
  for (int i = 0; i < 4; ++i)
    #pragma unroll
    for (int j = 0; j < 4; ++j) acc[i][j] = (f32x4){0.f,0.f,0.f,0.f};

  for (int k0 = 0; k0 < CDIM; k0 += 32){
    __syncthreads();
    const unsigned short* ga = A  + (size_t)(m0 + sr)*CDIM + k0 + sc*16;
    *(short8*)&aS[sr*40 + sc*16]     = *(const short8*)(ga);
    *(short8*)&aS[sr*40 + sc*16 + 8] = *(const short8*)(ga + 8);
    const unsigned short* gb = BT + (size_t)(n0 + sr)*CDIM + k0 + sc*16;
    *(short8*)&bS[sr*40 + sc*16]     = *(const short8*)(gb);
    *(short8*)&bS[sr*40 + sc*16 + 8] = *(const short8*)(gb + 8);
    __syncthreads();
    bf16x8 aF[4], bF[4];
    #pragma unroll
    for (int fm = 0; fm < 4; ++fm) aF[fm] = *(const bf16x8*)&aS[(wr*64 + fm*16 + lm)*40 + g*8];
    #pragma unroll
    for (int fn = 0; fn < 4; ++fn) bF[fn] = *(const bf16x8*)&bS[(wc*64 + fn*16 + lm)*40 + g*8];
    #pragma unroll
    for (int fm = 0; fm < 4; ++fm)
      #pragma unroll
      for (int fn = 0; fn < 4; ++fn)
        acc[fm][fn] = __builtin_amdgcn_mfma_f32_16x16x32_bf16(aF[fm], bF[fn], acc[fm][fn], 0, 0, 0);
  }

  int img = m0 >> 12;
  float psum[4] = {0.f,0.f,0.f,0.f};
  #pragma unroll
  for (int fn = 0; fn < 4; ++fn){
    int n = n0 + wc*64 + fn*16 + lm;
    float bias = b1[n];
    #pragma unroll
    for (int fm = 0; fm < 4; ++fm){
      int mbase = m0 + wr*64 + fm*16 + g*4;
      #pragma unroll
      for (int r = 0; r < 4; ++r){
        float v = acc[fm][fn][r] + bias;
        v = 0.5f * v * (1.f + erff(v * 0.70710678118654752f));   // exact GELU
        H[(size_t)(mbase + r)*FDIM + n] = bf16_rn(v);
        psum[fn] += v*v;
      }
    }
  }
  #pragma unroll
  for (int fn = 0; fn < 4; ++fn){
    float v = psum[fn];
    v += __shfl_xor(v, 16);
    v += __shfl_xor(v, 32);
    if (g == 0){
      int n = n0 + wc*64 + fn*16 + lm;
      atomicAdd(&grn[img*FDIM + n], v);
    }
  }
}

// ---------------- K7: GRN finalize -> S[n,f] = 1 + gamma[f]*nx
__global__ __launch_bounds__(256) void k_grn(const float* __restrict__ grn,
                                             const float* __restrict__ gamma,
                                             float* __restrict__ S){
  int n = blockIdx.x;
  const float* g = grn + n*FDIM;
  __shared__ float red[256];
  float p = 0.f;
  for (int f = threadIdx.x; f < FDIM; f += 256) p += sqrtf(g[f]);
  red[threadIdx.x] = p;
  __syncthreads();
  for (int s = 128; s > 0; s >>= 1){
    if (threadIdx.x < s) red[threadIdx.x] += red[threadIdx.x + s];
    __syncthreads();
  }
  float mean = red[0] * (1.f/FDIM);
  float inv = 1.f/(mean + 1e-6f);
  for (int f = threadIdx.x; f < FDIM; f += 256){
    float nx = sqrtf(g[f]) * inv;
    S[n*FDIM + f] = 1.f + gamma[f]*nx;
  }
}

// ---------------- K9: GEMM2: out[c,pix] = sum_f w2T[c,f]*(H[pix,f]*S[img,f]) + c2[c] + x  (M-dim=c, N-dim=pix)
__global__ __launch_bounds__(256) void k_gemm2(const unsigned short* __restrict__ W2T, // 384 x 1536
                                               const unsigned short* __restrict__ H,   // M x 1536
                                               const float* __restrict__ S,            // 8 x 1536
                                               const float* __restrict__ c2,
                                               const float* __restrict__ xg,
                                               float* __restrict__ out){
  __shared__ __align__(16) unsigned short aS[128*40];
  __shared__ __align__(16) unsigned short bS[128*40];
  int bid = blockIdx.x;
  int bm = bid % 3;            // channel tile (3 x 128 = 384)
  int bn = bid / 3;            // pixel tile (256 x 128 = 32768)
  int c0 = bm*128, p0 = bn*128;
  int img = p0 >> 12;
  const float* Simg = S + img*FDIM;
  int tid = threadIdx.x;
  int lane = tid & 63, wid = tid >> 6;
  int wr = wid >> 1, wc = wid & 1;
  int lm = lane & 15, g = lane >> 4;
  int sr = tid & 127, sc = tid >> 7;
  f32x4 acc[4][4];
  #pragma unroll
  for (int i = 0; i < 4; ++i)
    #pragma unroll
    for (int j = 0; j < 4; ++j) acc[i][j] = (f32x4){0.f,0.f,0.f,0.f};

  for (int k0 = 0; k0 < FDIM; k0 += 32){
    __syncthreads();
    const unsigned short* ga = W2T + (size_t)(c0 + sr)*FDIM + k0 + sc*16;
    *(short8*)&aS[sr*40 + sc*16]     = *(const short8*)(ga);
    *(short8*)&aS[sr*40 + sc*16 + 8] = *(const short8*)(ga + 8);
    const unsigned short* gb = H + (size_t)(p0 + sr)*FDIM + k0 + sc*16;
    short8 h0 = *(const short8*)(gb);
    short8 h1 = *(const short8*)(gb + 8);
    const float* sv = Simg + k0 + sc*16;
    short8 o0, o1;
    #pragma unroll
    for (int e = 0; e < 8; ++e){
      o0[e] = (short)bf16_rn(bf2f((unsigned short)h0[e]) * sv[e]);
      o1[e] = (short)bf16_rn(bf2f((unsigned short)h1[e]) * sv[e+8]);
    }
    *(short8*)&bS[sr*40 + sc*16]     = o0;
    *(short8*)&bS[sr*40 + sc*16 + 8] = o1;
    __syncthreads();
    bf16x8 aF[4], bF[4];
    #pragma unroll
    for (int fm = 0; fm < 4; ++fm) aF[fm] = *(const bf16x8*)&aS[(wr*64 + fm*16 + lm)*40 + g*8];
    #pragma unroll
    for (int fn = 0; fn < 4; ++fn) bF[fn] = *(const bf16x8*)&bS[(wc*64 + fn*16 + lm)*40 + g*8];
    #pragma unroll
    for (int fm = 0; fm < 4; ++fm)
      #pragma unroll
      for (int fn = 0; fn < 4; ++fn)
        acc[fm][fn] = __builtin_amdgcn_mfma_f32_16x16x32_bf16(aF[fm], bF[fn], acc[fm][fn], 0, 0, 0);
  }

  int sp0 = p0 & 4095;
  #pragma unroll
  for (int fn = 0; fn < 4; ++fn){
    int pixoff = sp0 + wc*64 + fn*16 + lm;
    #pragma unroll
    for (int fm = 0; fm < 4; ++fm){
      #pragma unroll
      for (int r = 0; r < 4; ++r){
        int c = c0 + wr*64 + fm*16 + g*4 + r;
        size_t addr = ((size_t)img*CDIM + c)*HW + pixoff;
        out[addr] = acc[fm][fn][r] + c2[c] + xg[addr];
      }
    }
  }
}

extern "C" void kernel_launch(void* const* d_in, const int* in_sizes, int n_in,
                              void* d_out, int out_size, void* d_ws, size_t ws_size,
                              hipStream_t stream) {
  const float* x    = (const float*)d_in[0];
  const float* wc   = (const float*)d_in[1];
  const float* kpe  = (const float*)d_in[2];
  const float* lnw  = (const float*)d_in[3];
  const float* lnb  = (const float*)d_in[4];
  const float* w1   = (const float*)d_in[5];
  const float* b1   = (const float*)d_in[6];
  const float* gam  = (const float*)d_in[7];
  const float* beta = (const float*)d_in[8];
  const float* w2   = (const float*)d_in[9];
  const float* b2   = (const float*)d_in[10];
  float* out = (float*)d_out;

  char* ws = (char*)d_ws;
  size_t o = 0;
  auto take = [&](size_t bytes)->char*{
    char* p = ws + o;
    o = (o + bytes + 511) & ~(size_t)511;
    return p;
  };
  // y (conv output, 50.3 MB) aliases d_out: it is fully consumed by k_ln before
  // k_gemm2 writes the real output (gemm2 reads only x/H/S/c2).
  float*          y     = out;
  float*          wfull = (float*)take((size_t)CDIM*2601*4);
  unsigned short* yn    = (unsigned short*)take((size_t)NPIX*CDIM*2);
  unsigned short* H     = (unsigned short*)take((size_t)NPIX*FDIM*2);
  unsigned short* w1T   = (unsigned short*)take((size_t)CDIM*FDIM*2);
  unsigned short* w2T   = (unsigned short*)take((size_t)CDIM*FDIM*2);
  float*          grn   = (float*)take(8*FDIM*4);
  float*          S     = (float*)take(8*FDIM*4);
  float*          c2    = (float*)take(CDIM*4);
  if (o > ws_size) return;   // workspace too small: leave output untouched (visible clean fail)

  k_build_w<<<CDIM, 256, 0, stream>>>(wc, kpe, wfull);
  k_conv<<<3072*2, 256, 0, stream>>>(x, wfull, y);
  k_ln<<<NPIX/256, 256, 0, stream>>>(y, lnw, lnb, yn);
  k_w1t<<<(CDIM*FDIM + 255)/256, 256, 0, stream>>>(w1, w1T);
  k_w2t<<<(CDIM*FDIM + 255)/256, 256, 0, stream>>>(w2, w2T);
  k_c2<<<3, 128, 0, stream>>>(w2, beta, b2, c2);
  hipMemsetAsync(grn, 0, 8*FDIM*4, stream);
  k_gemm1<<<(NPIX/128)*(FDIM/128), 256, 0, stream>>>(yn, w1T, b1, H, grn);
  k_grn<<<8, 256, 0, stream>>>(grn, gam, S);
  k_gemm2<<<3*(NPIX/128), 256, 0, stream>>>(w2T, H, S, c2, x, out);
}

// Round 6
// 605.205 us; speedup vs baseline: 1.7139x; 1.7139x over previous
//
#include <hip/hip_runtime.h>

#define CDIM 384
#define FDIM 1536
#define KK 51
#define RAD 25
#define NPIX 32768     // B*H*W
#define HW 4096        // 64*64

#define CSTR 136       // shifted-copy stride (elements)
#define OSTR 68        // out accumulator row stride (f32 words)
#define WSTR 72        // w_lds row stride (elements)

typedef float  f32x4  __attribute__((ext_vector_type(4)));
typedef short  short8 __attribute__((ext_vector_type(8)));
typedef __bf16 bf16x8 __attribute__((ext_vector_type(8)));
typedef unsigned short us4 __attribute__((ext_vector_type(4)));

// per-axis peripheral index: coords {0,1,2,4,8,16,25}, signed list P=13
__device__ __constant__ int AXIS[51] = {
  0,
  1,1,1,1,1,1,1,1,1,
  2,2,2,2,2,2,2,2,
  3,3,3,3,
  4,4,
  5,
  6,
  7,
  8,8,
  9,9,9,9,
  10,10,10,10,10,10,10,10,
  11,11,11,11,11,11,11,11,11,
  12
};

__device__ __forceinline__ unsigned short bf16_rn(float x){
  union { float f; unsigned u; } v; v.f = x;
  unsigned r = v.u + 0x7FFFu + ((v.u >> 16) & 1u);
  return (unsigned short)(r >> 16);
}
__device__ __forceinline__ float bf2f(unsigned short h){
  union { unsigned u; float f; } v; v.u = ((unsigned)h) << 16; return v.f;
}

// ---------------- K0: expand per-channel kernel: w[c,i,j] = wc[c, cell(i,j)] + kpe[i,j]
__global__ __launch_bounds__(256) void k_build_w(const float* __restrict__ wc,
                                                 const float* __restrict__ kpe,
                                                 float* __restrict__ wfull){
  int c = blockIdx.x;
  const float* wcc = wc + c*169;
  float* wo = wfull + (size_t)c*2601;
  for (int idx = threadIdx.x; idx < 2601; idx += 256){
    int i = idx / 51, j = idx - i*51;
    wo[idx] = wcc[AXIS[i]*13 + AXIS[j]] + kpe[idx];
  }
}

// ---------------- K1: depthwise conv 51x51 via MFMA row-Toeplitz scatter.
// One block = one (b,c) image. For each input row r:
//   D[q,i] = sum_j x[r, q+j-25] * w[i,j]   (16x16x32 bf16 MFMA, A=Toeplitz, B=w rows)
//   out[r+25-i, q] += D[q,i]               (LDS RMW; q-partitioned across waves -> race-free)
__global__ __launch_bounds__(256) void k_conv_mfma(const float* __restrict__ x,
                                                   const float* __restrict__ wfull,
                                                   float* __restrict__ y){
  __shared__ __align__(16) float outb[64*OSTR];             // 17408 B accumulator
  __shared__ __align__(16) unsigned short wl[64*WSTR];      // 9216 B  w (bf16, zero-padded)
  __shared__ __align__(16) unsigned short bufs[2][8*CSTR];  // 2x2176 B shifted row copies
  int img = blockIdx.x;                 // b*384 + c
  int ch  = img % CDIM;
  const float* xim = x + (size_t)img*HW;
  const float* wch = wfull + (size_t)ch*2601;
  int tid = threadIdx.x;
  int lane = tid & 63, wid = tid >> 6;  // wid = q-tile (mt)
  int li = lane & 15, g = lane >> 4;    // frag row / 8-group

  // zero accumulator (64*68 = 4352 words = 1088 f32x4, exact)
  for (int i = tid; i < 1088; i += 256)
    *(f32x4*)&outb[i*4] = (f32x4){0.f,0.f,0.f,0.f};
  // fill w_lds 64x64 (rows/cols >= 51 zero)
  for (int e = tid; e < 64*64; e += 256){
    int i = e >> 6, j = e & 63;
    float v = (i < 51 && j < 51) ? wch[i*51 + j] : 0.f;
    wl[i*WSTR + j] = bf16_rn(v);
  }
  // stage row 0 into bufs[0]: copy c holds L[t+c], L[u] = x[r, u-25] (zero-padded)
  {
    int c = tid >> 5, t0 = (tid & 31) << 2;
    us4 o;
    #pragma unroll
    for (int e = 0; e < 4; ++e){
      int xi = t0 + c + e - 25;
      float v = (xi >= 0 && xi < 64) ? xim[xi] : 0.f;
      o[e] = bf16_rn(v);
    }
    *(us4*)&bufs[0][c*CSTR + t0] = o;
  }
  __syncthreads();

  // B-fragments (w rows), loaded once: lane li holds w[i = nt*16+li, j = kt*32 + g*8 + e]
  bf16x8 Bf[4][2];
  #pragma unroll
  for (int nt = 0; nt < 4; ++nt)
    #pragma unroll
    for (int kt = 0; kt < 2; ++kt)
      Bf[nt][kt] = *(const bf16x8*)&wl[(nt*16 + li)*WSTR + kt*32 + g*8];

  for (int r = 0; r < 64; ++r){
    const unsigned short* bb = bufs[r & 1];
    // A-fragments: lane li holds x[r, (wid*16+li) + (kt*32+g*8+e) - 25]
    bf16x8 Af[2];
    #pragma unroll
    for (int kt = 0; kt < 2; ++kt){
      int u0 = wid*16 + kt*32 + g*8 + li;
      int c  = li & 7;
      Af[kt] = *(const bf16x8*)&bb[c*CSTR + (u0 - c)];
    }
    #pragma unroll
    for (int nt = 0; nt < 4; ++nt){
      int pmax = r + 25 - nt*16;            // p for i = nt*16 (li=0)
      if (pmax < 0 || pmax - 15 > 63) continue;   // tile fully out of range (wave-uniform)
      f32x4 D = {0.f,0.f,0.f,0.f};
      D = __builtin_amdgcn_mfma_f32_16x16x32_bf16(Af[0], Bf[nt][0], D, 0, 0, 0);
      D = __builtin_amdgcn_mfma_f32_16x16x32_bf16(Af[1], Bf[nt][1], D, 0, 0, 0);
      // lane holds D[q = wid*16 + g*4 + reg, i = nt*16 + li] -> out[p = r+25-i][q]
      int p = pmax - li;
      if (p >= 0 && p < 64){
        float* oa = &outb[p*OSTR + wid*16 + g*4];
        f32x4 old = *(const f32x4*)oa;
        *(f32x4*)oa = old + D;
      }
    }
    // stage next row (double-buffered; barrier below orders it vs next iter's reads)
    if (r + 1 < 64){
      int c = tid >> 5, t0 = (tid & 31) << 2;
      const float* xr = xim + (r + 1)*64;
      us4 o;
      #pragma unroll
      for (int e = 0; e < 4; ++e){
        int xi = t0 + c + e - 25;
        float v = (xi >= 0 && xi < 64) ? xr[xi] : 0.f;
        o[e] = bf16_rn(v);
      }
      *(us4*)&bufs[(r + 1) & 1][c*CSTR + t0] = o;
    }
    __syncthreads();
  }

  // epilogue: out -> global (coalesced f32x4)
  float* yo = y + (size_t)img*HW;
  #pragma unroll
  for (int k = 0; k < 4; ++k){
    int pix = k*1024 + tid*4;
    int p = pix >> 6, q = pix & 63;
    *(f32x4*)(yo + pix) = *(const f32x4*)&outb[p*OSTR + q];
  }
}

// ---------------- K2: LayerNorm over C (NCHW f32 -> NHWC bf16), LDS transpose for coalesced writes
__global__ __launch_bounds__(256) void k_ln(const float* __restrict__ y,
                                            const float* __restrict__ lnw,
                                            const float* __restrict__ lnb,
                                            unsigned short* __restrict__ yn){
  __shared__ unsigned short tile[4][64*66];
  int tid = threadIdx.x, lane = tid & 63, wid = tid >> 6;
  int pg = blockIdx.x*256 + wid*64 + lane;        // pixel id
  int b = pg >> 12, sp = pg & 4095;
  const float* yb = y + (size_t)b*CDIM*HW + sp;
  float sum = 0.f, sq = 0.f;
  for (int c = 0; c < CDIM; ++c){
    float v = yb[(size_t)c*HW];
    sum += v; sq += v*v;
  }
  float mu   = sum * (1.f/CDIM);
  float var  = sq  * (1.f/CDIM) - mu*mu;
  float rstd = rsqrtf(var + 1e-6f);
  unsigned short* tl = tile[wid];
  int pixbase = blockIdx.x*256 + wid*64;
  for (int c0 = 0; c0 < CDIM; c0 += 64){
    #pragma unroll 4
    for (int cc = 0; cc < 64; ++cc){
      int c = c0 + cc;
      float v = (yb[(size_t)c*HW] - mu) * rstd * lnw[c] + lnb[c];
      tl[cc*66 + lane] = bf16_rn(v);
    }
    // same-wave LDS RAW: compiler inserts waitcnt
    for (int p = 0; p < 64; ++p){
      yn[(size_t)(pixbase + p)*CDIM + c0 + lane] = tl[lane*66 + p];
    }
  }
}

// ---------------- K4/K5: weight transposes to bf16
__global__ __launch_bounds__(256) void k_w1t(const float* __restrict__ w1, unsigned short* __restrict__ w1T){
  int idx = blockIdx.x*256 + threadIdx.x;
  if (idx < CDIM*FDIM){ int c = idx / FDIM, f = idx - c*FDIM; w1T[(size_t)f*CDIM + c] = bf16_rn(w1[idx]); }
}
__global__ __launch_bounds__(256) void k_w2t(const float* __restrict__ w2, unsigned short* __restrict__ w2T){
  int idx = blockIdx.x*256 + threadIdx.x;
  if (idx < CDIM*FDIM){ int f = idx / CDIM, c = idx - f*CDIM; w2T[(size_t)c*FDIM + f] = bf16_rn(w2[idx]); }
}

// ---------------- K8: c2[c] = b2[c] + sum_f beta[f]*w2[f,c]
__global__ __launch_bounds__(128) void k_c2(const float* __restrict__ w2,
                                            const float* __restrict__ beta,
                                            const float* __restrict__ b2,
                                            float* __restrict__ c2){
  int c = blockIdx.x*128 + threadIdx.x;
  if (c < CDIM){
    float s = b2[c];
    for (int f = 0; f < FDIM; ++f) s += beta[f] * w2[(size_t)f*CDIM + c];
    c2[c] = s;
  }
}

// ---------------- K6: GEMM1 (M x 384) x (384 x 1536) + b1 + exact GELU -> H bf16; GRN partial sums
__global__ __launch_bounds__(256) void k_gemm1(const unsigned short* __restrict__ A,   // yn M x 384
                                               const unsigned short* __restrict__ BT,  // w1T 1536 x 384
                                               const float* __restrict__ b1,
                                               unsigned short* __restrict__ H,         // M x 1536
                                               float* __restrict__ grn){               // 8 x 1536
  __shared__ __align__(16) unsigned short aS[128*40];
  __shared__ __align__(16) unsigned short bS[128*40];
  int bid = blockIdx.x;
  int bm = bid & 255, bn = bid >> 8;
  int m0 = bm*128, n0 = bn*128;
  int tid = threadIdx.x;
  int lane = tid & 63, wid = tid >> 6;
  int wr = wid >> 1, wc = wid & 1;
  int lm = lane & 15, g = lane >> 4;
  int sr = tid & 127, sc = tid >> 7;
  f32x4 acc[4][4];
  #pragma unroll
  for (int i = 0; i < 4; ++i)
    #pragma unroll
    for (int j = 0; j < 4; ++j) acc[i][j] = (f32x4){0.f,0.f,0.f,0.f};

  for (int k0 = 0; k0 < CDIM; k0 += 32){
    __syncthreads();
    const unsigned short* ga = A  + (size_t)(m0 + sr)*CDIM + k0 + sc*16;
    *(short8*)&aS[sr*40 + sc*16]     = *(const short8*)(ga);
    *(short8*)&aS[sr*40 + sc*16 + 8] = *(const short8*)(ga + 8);
    const unsigned short* gb = BT + (size_t)(n0 + sr)*CDIM + k0 + sc*16;
    *(short8*)&bS[sr*40 + sc*16]     = *(const short8*)(gb);
    *(short8*)&bS[sr*40 + sc*16 + 8] = *(const short8*)(gb + 8);
    __syncthreads();
    bf16x8 aF[4], bF[4];
    #pragma unroll
    for (int fm = 0; fm < 4; ++fm) aF[fm] = *(const bf16x8*)&aS[(wr*64 + fm*16 + lm)*40 + g*8];
    #pragma unroll
    for (int fn = 0; fn < 4; ++fn) bF[fn] = *(const bf16x8*)&bS[(wc*64 + fn*16 + lm)*40 + g*8];
    #pragma unroll
    for (int fm = 0; fm < 4; ++fm)
      #pragma unroll
      for (int fn = 0; fn < 4; ++fn)
        acc[fm][fn] = __builtin_amdgcn_mfma_f32_16x16x32_bf16(aF[fm], bF[fn], acc[fm][fn], 0, 0, 0);
  }

  int img = m0 >> 12;
  float psum[4] = {0.f,0.f,0.f,0.f};
  #pragma unroll
  for (int fn = 0; fn < 4; ++fn){
    int n = n0 + wc*64 + fn*16 + lm;
    float bias = b1[n];
    #pragma unroll
    for (int fm = 0; fm < 4; ++fm){
      int mbase = m0 + wr*64 + fm*16 + g*4;
      #pragma unroll
      for (int r = 0; r < 4; ++r){
        float v = acc[fm][fn][r] + bias;
        v = 0.5f * v * (1.f + erff(v * 0.70710678118654752f));   // exact GELU
        H[(size_t)(mbase + r)*FDIM + n] = bf16_rn(v);
        psum[fn] += v*v;
      }
    }
  }
  #pragma unroll
  for (int fn = 0; fn < 4; ++fn){
    float v = psum[fn];
    v += __shfl_xor(v, 16);
    v += __shfl_xor(v, 32);
    if (g == 0){
      int n = n0 + wc*64 + fn*16 + lm;
      atomicAdd(&grn[img*FDIM + n], v);
    }
  }
}

// ---------------- K7: GRN finalize -> S[n,f] = 1 + gamma[f]*nx
__global__ __launch_bounds__(256) void k_grn(const float* __restrict__ grn,
                                             const float* __restrict__ gamma,
                                             float* __restrict__ S){
  int n = blockIdx.x;
  const float* g = grn + n*FDIM;
  __shared__ float red[256];
  float p = 0.f;
  for (int f = threadIdx.x; f < FDIM; f += 256) p += sqrtf(g[f]);
  red[threadIdx.x] = p;
  __syncthreads();
  for (int s = 128; s > 0; s >>= 1){
    if (threadIdx.x < s) red[threadIdx.x] += red[threadIdx.x + s];
    __syncthreads();
  }
  float mean = red[0] * (1.f/FDIM);
  float inv = 1.f/(mean + 1e-6f);
  for (int f = threadIdx.x; f < FDIM; f += 256){
    float nx = sqrtf(g[f]) * inv;
    S[n*FDIM + f] = 1.f + gamma[f]*nx;
  }
}

// ---------------- K9: GEMM2: out[c,pix] = sum_f w2T[c,f]*(H[pix,f]*S[img,f]) + c2[c] + x  (M-dim=c, N-dim=pix)
__global__ __launch_bounds__(256) void k_gemm2(const unsigned short* __restrict__ W2T, // 384 x 1536
                                               const unsigned short* __restrict__ H,   // M x 1536
                                               const float* __restrict__ S,            // 8 x 1536
                                               const float* __restrict__ c2,
                                               const float* __restrict__ xg,
                                               float* __restrict__ out){
  __shared__ __align__(16) unsigned short aS[128*40];
  __shared__ __align__(16) unsigned short bS[128*40];
  int bid = blockIdx.x;
  int bm = bid % 3;            // channel tile (3 x 128 = 384)
  int bn = bid / 3;            // pixel tile (256 x 128 = 32768)
  int c0 = bm*128, p0 = bn*128;
  int img = p0 >> 12;
  const float* Simg = S + img*FDIM;
  int tid = threadIdx.x;
  int lane = tid & 63, wid = tid >> 6;
  int wr = wid >> 1, wc = wid & 1;
  int lm = lane & 15, g = lane >> 4;
  int sr = tid & 127, sc = tid >> 7;
  f32x4 acc[4][4];
  #pragma unroll
  for (int i = 0; i < 4; ++i)
    #pragma unroll
    for (int j = 0; j < 4; ++j) acc[i][j] = (f32x4){0.f,0.f,0.f,0.f};

  for (int k0 = 0; k0 < FDIM; k0 += 32){
    __syncthreads();
    const unsigned short* ga = W2T + (size_t)(c0 + sr)*FDIM + k0 + sc*16;
    *(short8*)&aS[sr*40 + sc*16]     = *(const short8*)(ga);
    *(short8*)&aS[sr*40 + sc*16 + 8] = *(const short8*)(ga + 8);
    const unsigned short* gb = H + (size_t)(p0 + sr)*FDIM + k0 + sc*16;
    short8 h0 = *(const short8*)(gb);
    short8 h1 = *(const short8*)(gb + 8);
    const float* sv = Simg + k0 + sc*16;
    short8 o0, o1;
    #pragma unroll
    for (int e = 0; e < 8; ++e){
      o0[e] = (short)bf16_rn(bf2f((unsigned short)h0[e]) * sv[e]);
      o1[e] = (short)bf16_rn(bf2f((unsigned short)h1[e]) * sv[e+8]);
    }
    *(short8*)&bS[sr*40 + sc*16]     = o0;
    *(short8*)&bS[sr*40 + sc*16 + 8] = o1;
    __syncthreads();
    bf16x8 aF[4], bF[4];
    #pragma unroll
    for (int fm = 0; fm < 4; ++fm) aF[fm] = *(const bf16x8*)&aS[(wr*64 + fm*16 + lm)*40 + g*8];
    #pragma unroll
    for (int fn = 0; fn < 4; ++fn) bF[fn] = *(const bf16x8*)&bS[(wc*64 + fn*16 + lm)*40 + g*8];
    #pragma unroll
    for (int fm = 0; fm < 4; ++fm)
      #pragma unroll
      for (int fn = 0; fn < 4; ++fn)
        acc[fm][fn] = __builtin_amdgcn_mfma_f32_16x16x32_bf16(aF[fm], bF[fn], acc[fm][fn], 0, 0, 0);
  }

  int sp0 = p0 & 4095;
  #pragma unroll
  for (int fn = 0; fn < 4; ++fn){
    int pixoff = sp0 + wc*64 + fn*16 + lm;
    #pragma unroll
    for (int fm = 0; fm < 4; ++fm){
      #pragma unroll
      for (int r = 0; r < 4; ++r){
        int c = c0 + wr*64 + fm*16 + g*4 + r;
        size_t addr = ((size_t)img*CDIM + c)*HW + pixoff;
        out[addr] = acc[fm][fn][r] + c2[c] + xg[addr];
      }
    }
  }
}

extern "C" void kernel_launch(void* const* d_in, const int* in_sizes, int n_in,
                              void* d_out, int out_size, void* d_ws, size_t ws_size,
                              hipStream_t stream) {
  const float* x    = (const float*)d_in[0];
  const float* wc   = (const float*)d_in[1];
  const float* kpe  = (const float*)d_in[2];
  const float* lnw  = (const float*)d_in[3];
  const float* lnb  = (const float*)d_in[4];
  const float* w1   = (const float*)d_in[5];
  const float* b1   = (const float*)d_in[6];
  const float* gam  = (const float*)d_in[7];
  const float* beta = (const float*)d_in[8];
  const float* w2   = (const float*)d_in[9];
  const float* b2   = (const float*)d_in[10];
  float* out = (float*)d_out;

  char* ws = (char*)d_ws;
  size_t o = 0;
  auto take = [&](size_t bytes)->char*{
    char* p = ws + o;
    o = (o + bytes + 511) & ~(size_t)511;
    return p;
  };
  // y (conv output, 50.3 MB) aliases d_out: it is fully consumed by k_ln before
  // k_gemm2 writes the real output (gemm2 reads only x/H/S/c2).
  float*          y     = out;
  float*          wfull = (float*)take((size_t)CDIM*2601*4);
  unsigned short* yn    = (unsigned short*)take((size_t)NPIX*CDIM*2);
  unsigned short* H     = (unsigned short*)take((size_t)NPIX*FDIM*2);
  unsigned short* w1T   = (unsigned short*)take((size_t)CDIM*FDIM*2);
  unsigned short* w2T   = (unsigned short*)take((size_t)CDIM*FDIM*2);
  float*          grn   = (float*)take(8*FDIM*4);
  float*          S     = (float*)take(8*FDIM*4);
  float*          c2    = (float*)take(CDIM*4);
  if (o > ws_size) return;   // workspace too small: leave output untouched (visible clean fail)

  k_build_w<<<CDIM, 256, 0, stream>>>(wc, kpe, wfull);
  k_conv_mfma<<<3072, 256, 0, stream>>>(x, wfull, y);
  k_ln<<<NPIX/256, 256, 0, stream>>>(y, lnw, lnb, yn);
  k_w1t<<<(CDIM*FDIM + 255)/256, 256, 0, stream>>>(w1, w1T);
  k_w2t<<<(CDIM*FDIM + 255)/256, 256, 0, stream>>>(w2, w2T);
  k_c2<<<3, 128, 0, stream>>>(w2, beta, b2, c2);
  hipMemsetAsync(grn, 0, 8*FDIM*4, stream);
  k_gemm1<<<(NPIX/128)*(FDIM/128), 256, 0, stream>>>(yn, w1T, b1, H, grn);
  k_grn<<<8, 256, 0, stream>>>(grn, gam, S);
  k_gemm2<<<3*(NPIX/128), 256, 0, stream>>>(w2T, H, S, c2, x, out);
}

// Round 7
// 500.812 us; speedup vs baseline: 2.0711x; 1.2084x over previous
//
#include <hip/hip_runtime.h>

#define CDIM 384
#define FDIM 1536
#define KK 51
#define RAD 25
#define NPIX 32768     // B*H*W
#define HW 4096        // 64*64

#define CSTR 136       // shifted-copy stride (elements)
#define OSTR 68        // out accumulator row stride (f32 words)

typedef float  f32x4  __attribute__((ext_vector_type(4)));
typedef short  short8 __attribute__((ext_vector_type(8)));
typedef __bf16 bf16x8 __attribute__((ext_vector_type(8)));
typedef unsigned short us4 __attribute__((ext_vector_type(4)));

// per-axis peripheral index: coords {0,1,2,4,8,16,25}, signed list P=13
__device__ __constant__ int AXIS[51] = {
  0,
  1,1,1,1,1,1,1,1,1,
  2,2,2,2,2,2,2,2,
  3,3,3,3,
  4,4,
  5,
  6,
  7,
  8,8,
  9,9,9,9,
  10,10,10,10,10,10,10,10,
  11,11,11,11,11,11,11,11,11,
  12
};

__device__ __forceinline__ unsigned short bf16_rn(float x){
  union { float f; unsigned u; } v; v.f = x;
  unsigned r = v.u + 0x7FFFu + ((v.u >> 16) & 1u);
  return (unsigned short)(r >> 16);
}
__device__ __forceinline__ float bf2f(unsigned short h){
  union { unsigned u; float f; } v; v.u = ((unsigned)h) << 16; return v.f;
}

// ---------------- K0: expand per-channel kernel: w[c,i,j] = wc[c, cell(i,j)] + kpe[i,j]
__global__ __launch_bounds__(256) void k_build_w(const float* __restrict__ wc,
                                                 const float* __restrict__ kpe,
                                                 float* __restrict__ wfull){
  int c = blockIdx.x;
  const float* wcc = wc + c*169;
  float* wo = wfull + (size_t)c*2601;
  for (int idx = threadIdx.x; idx < 2601; idx += 256){
    int i = idx / 51, j = idx - i*51;
    wo[idx] = wcc[AXIS[i]*13 + AXIS[j]] + kpe[idx];
  }
}

// stage one input row r as 8 shifted bf16 copies: copy c, position t holds L[t+c],
// L[u] = x[r, u-25] zero-padded. Only positions 0..127 per copy are ever read.
__device__ __forceinline__ void stage_row(unsigned short* dst, const float* xim,
                                          int r, int lane){
  const float* xr = xim + r*64;
  #pragma unroll
  for (int it = 0; it < 4; ++it){
    int idx = lane + it*64;            // 0..255 us4 units (8 copies x 32)
    int c = idx >> 5, t0 = (idx & 31) << 2;
    us4 o;
    #pragma unroll
    for (int e = 0; e < 4; ++e){
      int xi = t0 + e + c - 25;
      float v = (xi >= 0 && xi < 64) ? xr[xi] : 0.f;
      o[e] = bf16_rn(v);
    }
    *(us4*)&dst[c*CSTR + t0] = o;
  }
}

// ---------------- K1: depthwise conv 51x51 via MFMA row-Toeplitz scatter,
// 4-row alignment-class batching. One block = one (b,c) image, 16 phases.
// Phase ph processes rows {ph, ph+16, ph+32, ph+48}. Rows 16 apart have
// identically-aligned scatter tiles: class d = s-nt has pmax = ph+25+16d for
// every s, so contributions accumulate in the MFMA C-chain and commit with a
// single b128 RMW per class. Classes have disjoint p-ranges; waves are
// q-partitioned -> all RMWs race-free, one barrier per phase.
__global__ __launch_bounds__(256) void k_conv_mfma(const float* __restrict__ x,
                                                   const float* __restrict__ wfull,
                                                   float* __restrict__ y){
  __shared__ __align__(16) float outb[64*OSTR];              // 17408 B accumulator
  __shared__ __align__(16) unsigned short bufs[2][4][1088];  // 17408 B row copies
  int img = blockIdx.x;                 // b*384 + c
  int ch  = img % CDIM;
  const float* xim = x + (size_t)img*HW;
  const float* wch = wfull + (size_t)ch*2601;
  int tid = threadIdx.x;
  int lane = tid & 63, wid = tid >> 6;  // wid = q-tile
  int li = lane & 15, g = lane >> 4;

  // zero accumulator (64*68 = 4352 words = 1088 f32x4, exact)
  for (int i = tid; i < 1088; i += 256)
    *(f32x4*)&outb[i*4] = (f32x4){0.f,0.f,0.f,0.f};

  // B fragments (w rows) straight from global, bf16, zero-padded:
  // lane li holds w[i = nt*16+li, j = kt*32 + g*8 + e]
  bf16x8 Bf[4][2];
  #pragma unroll
  for (int nt = 0; nt < 4; ++nt){
    int i = nt*16 + li;
    #pragma unroll
    for (int kt = 0; kt < 2; ++kt){
      union { bf16x8 v; unsigned short u[8]; } tmp;
      #pragma unroll
      for (int e = 0; e < 8; ++e){
        int j = kt*32 + g*8 + e;
        float v = (i < 51 && j < 51) ? wch[i*51 + j] : 0.f;
        tmp.u[e] = bf16_rn(v);
      }
      Bf[nt][kt] = tmp.v;
    }
  }

  // stage phase 0: wave wid stages row 16*wid
  stage_row(&bufs[0][wid][0], xim, 16*wid, lane);
  __syncthreads();

  #pragma unroll 1
  for (int ph = 0; ph < 16; ++ph){
    // A fragments for the 4 rows of this phase:
    // lane li holds x[r, (wid*16+li) + (kt*32+g*8+e) - 25]
    bf16x8 Af[4][2];
    #pragma unroll
    for (int s = 0; s < 4; ++s){
      const unsigned short* bb = &bufs[ph & 1][s][0];
      #pragma unroll
      for (int kt = 0; kt < 2; ++kt){
        int u0 = wid*16 + kt*32 + g*8 + li;
        int c  = li & 7;
        Af[s][kt] = *(const bf16x8*)&bb[c*CSTR + (u0 - c)];
      }
    }
    // prefetch next phase's rows into the other buffer
    if (ph + 1 < 16) stage_row(&bufs[(ph + 1) & 1][wid][0], xim, ph + 1 + 16*wid, lane);

    // 6 alignment classes d = s - nt in [-2, 3]
    #pragma unroll
    for (int dd = 0; dd < 6; ++dd){
      int d = dd - 2;
      int pmax = ph + 25 + 16*d;
      if (pmax < 0 || pmax > 78) continue;     // no valid lane (wave-uniform)
      f32x4 V = {0.f,0.f,0.f,0.f};
      #pragma unroll
      for (int s = 0; s < 4; ++s){
        int nt = s - d;
        if (nt < 0 || nt > 3) continue;        // compile-time after unroll
        V = __builtin_amdgcn_mfma_f32_16x16x32_bf16(Af[s][0], Bf[nt][0], V, 0, 0, 0);
        V = __builtin_amdgcn_mfma_f32_16x16x32_bf16(Af[s][1], Bf[nt][1], V, 0, 0, 0);
      }
      // lane holds V[q = wid*16 + g*4 + reg] for out row p = pmax - li
      int p = pmax - li;
      if (p >= 0 && p < 64){
        float* oa = &outb[p*OSTR + wid*16 + g*4];
        f32x4 old = *(const f32x4*)oa;
        *(f32x4*)oa = old + V;
      }
    }
    __syncthreads();
  }

  // epilogue: out -> global (coalesced f32x4)
  float* yo = y + (size_t)img*HW;
  #pragma unroll
  for (int k = 0; k < 4; ++k){
    int pix = k*1024 + tid*4;
    int p = pix >> 6, q = pix & 63;
    *(f32x4*)(yo + pix) = *(const f32x4*)&outb[p*OSTR + q];
  }
}

// ---------------- K2: LayerNorm over C (NCHW f32 -> NHWC bf16), LDS transpose for coalesced writes
__global__ __launch_bounds__(256) void k_ln(const float* __restrict__ y,
                                            const float* __restrict__ lnw,
                                            const float* __restrict__ lnb,
                                            unsigned short* __restrict__ yn){
  __shared__ unsigned short tile[4][64*66];
  int tid = threadIdx.x, lane = tid & 63, wid = tid >> 6;
  int pg = blockIdx.x*256 + wid*64 + lane;        // pixel id
  int b = pg >> 12, sp = pg & 4095;
  const float* yb = y + (size_t)b*CDIM*HW + sp;
  float sum = 0.f, sq = 0.f;
  for (int c = 0; c < CDIM; ++c){
    float v = yb[(size_t)c*HW];
    sum += v; sq += v*v;
  }
  float mu   = sum * (1.f/CDIM);
  float var  = sq  * (1.f/CDIM) - mu*mu;
  float rstd = rsqrtf(var + 1e-6f);
  unsigned short* tl = tile[wid];
  int pixbase = blockIdx.x*256 + wid*64;
  for (int c0 = 0; c0 < CDIM; c0 += 64){
    #pragma unroll 4
    for (int cc = 0; cc < 64; ++cc){
      int c = c0 + cc;
      float v = (yb[(size_t)c*HW] - mu) * rstd * lnw[c] + lnb[c];
      tl[cc*66 + lane] = bf16_rn(v);
    }
    // same-wave LDS RAW: compiler inserts waitcnt
    for (int p = 0; p < 64; ++p){
      yn[(size_t)(pixbase + p)*CDIM + c0 + lane] = tl[lane*66 + p];
    }
  }
}

// ---------------- K4/K5: weight transposes to bf16
__global__ __launch_bounds__(256) void k_w1t(const float* __restrict__ w1, unsigned short* __restrict__ w1T){
  int idx = blockIdx.x*256 + threadIdx.x;
  if (idx < CDIM*FDIM){ int c = idx / FDIM, f = idx - c*FDIM; w1T[(size_t)f*CDIM + c] = bf16_rn(w1[idx]); }
}
__global__ __launch_bounds__(256) void k_w2t(const float* __restrict__ w2, unsigned short* __restrict__ w2T){
  int idx = blockIdx.x*256 + threadIdx.x;
  if (idx < CDIM*FDIM){ int f = idx / CDIM, c = idx - f*CDIM; w2T[(size_t)c*FDIM + f] = bf16_rn(w2[idx]); }
}

// ---------------- K8: c2[c] = b2[c] + sum_f beta[f]*w2[f,c]  (block per c, parallel over f)
__global__ __launch_bounds__(256) void k_c2(const float* __restrict__ w2,
                                            const float* __restrict__ beta,
                                            const float* __restrict__ b2,
                                            float* __restrict__ c2){
  int c = blockIdx.x;
  __shared__ float red[256];
  float s = 0.f;
  for (int f = threadIdx.x; f < FDIM; f += 256) s += beta[f] * w2[(size_t)f*CDIM + c];
  red[threadIdx.x] = s;
  __syncthreads();
  for (int t = 128; t > 0; t >>= 1){
    if (threadIdx.x < t) red[threadIdx.x] += red[threadIdx.x + t];
    __syncthreads();
  }
  if (threadIdx.x == 0) c2[c] = red[0] + b2[c];
}

// ---------------- K6: GEMM1 (M x 384) x (384 x 1536) + b1 + exact GELU -> H bf16; GRN partial sums
__global__ __launch_bounds__(256) void k_gemm1(const unsigned short* __restrict__ A,   // yn M x 384
                                               const unsigned short* __restrict__ BT,  // w1T 1536 x 384
                                               const float* __restrict__ b1,
                                               unsigned short* __restrict__ H,         // M x 1536
                                               float* __restrict__ grn){               // 8 x 1536
  __shared__ __align__(16) unsigned short aS[128*40];
  __shared__ __align__(16) unsigned short bS[128*40];
  int bid = blockIdx.x;
  int bm = bid & 255, bn = bid >> 8;
  int m0 = bm*128, n0 = bn*128;
  int tid = threadIdx.x;
  int lane = tid & 63, wid = tid >> 6;
  int wr = wid >> 1, wc = wid & 1;
  int lm = lane & 15, g = lane >> 4;
  int sr = tid & 127, sc = tid >> 7;
  f32x4 acc[4][4];
  #pragma unroll
  for (int i = 0; i < 4; ++i)
    #pragma unroll
    for (int j = 0; j < 4; ++j) acc[i][j] = (f32x4){0.f,0.f,0.f,0.f};

  for (int k0 = 0; k0 < CDIM; k0 += 32){
    __syncthreads();
    const unsigned short* ga = A  + (size_t)(m0 + sr)*CDIM + k0 + sc*16;
    *(short8*)&aS[sr*40 + sc*16]     = *(const short8*)(ga);
    *(short8*)&aS[sr*40 + sc*16 + 8] = *(const short8*)(ga + 8);
    const unsigned short* gb = BT + (size_t)(n0 + sr)*CDIM + k0 + sc*16;
    *(short8*)&bS[sr*40 + sc*16]     = *(const short8*)(gb);
    *(short8*)&bS[sr*40 + sc*16 + 8] = *(const short8*)(gb + 8);
    __syncthreads();
    bf16x8 aF[4], bF[4];
    #pragma unroll
    for (int fm = 0; fm < 4; ++fm) aF[fm] = *(const bf16x8*)&aS[(wr*64 + fm*16 + lm)*40 + g*8];
    #pragma unroll
    for (int fn = 0; fn < 4; ++fn) bF[fn] = *(const bf16x8*)&bS[(wc*64 + fn*16 + lm)*40 + g*8];
    #pragma unroll
    for (int fm = 0; fm < 4; ++fm)
      #pragma unroll
      for (int fn = 0; fn < 4; ++fn)
        acc[fm][fn] = __builtin_amdgcn_mfma_f32_16x16x32_bf16(aF[fm], bF[fn], acc[fm][fn], 0, 0, 0);
  }

  int img = m0 >> 12;
  float psum[4] = {0.f,0.f,0.f,0.f};
  #pragma unroll
  for (int fn = 0; fn < 4; ++fn){
    int n = n0 + wc*64 + fn*16 + lm;
    float bias = b1[n];
    #pragma unroll
    for (int fm = 0; fm < 4; ++fm){
      int mbase = m0 + wr*64 + fm*16 + g*4;
      #pragma unroll
      for (int r = 0; r < 4; ++r){
        float v = acc[fm][fn][r] + bias;
        v = 0.5f * v * (1.f + erff(v * 0.70710678118654752f));   // exact GELU
        H[(size_t)(mbase + r)*FDIM + n] = bf16_rn(v);
        psum[fn] += v*v;
      }
    }
  }
  #pragma unroll
  for (int fn = 0; fn < 4; ++fn){
    float v = psum[fn];
    v += __shfl_xor(v, 16);
    v += __shfl_xor(v, 32);
    if (g == 0){
      int n = n0 + wc*64 + fn*16 + lm;
      atomicAdd(&grn[img*FDIM + n], v);
    }
  }
}

// ---------------- K7: GRN finalize -> S[n,f] = 1 + gamma[f]*nx
__global__ __launch_bounds__(256) void k_grn(const float* __restrict__ grn,
                                             const float* __restrict__ gamma,
                                             float* __restrict__ S){
  int n = blockIdx.x;
  const float* g = grn + n*FDIM;
  __shared__ float red[256];
  float p = 0.f;
  for (int f = threadIdx.x; f < FDIM; f += 256) p += sqrtf(g[f]);
  red[threadIdx.x] = p;
  __syncthreads();
  for (int s = 128; s > 0; s >>= 1){
    if (threadIdx.x < s) red[threadIdx.x] += red[threadIdx.x + s];
    __syncthreads();
  }
  float mean = red[0] * (1.f/FDIM);
  float inv = 1.f/(mean + 1e-6f);
  for (int f = threadIdx.x; f < FDIM; f += 256){
    float nx = sqrtf(g[f]) * inv;
    S[n*FDIM + f] = 1.f + gamma[f]*nx;
  }
}

// ---------------- K9: GEMM2: out[c,pix] = sum_f w2T[c,f]*(H[pix,f]*S[img,f]) + c2[c] + x  (M-dim=c, N-dim=pix)
__global__ __launch_bounds__(256) void k_gemm2(const unsigned short* __restrict__ W2T, // 384 x 1536
                                               const unsigned short* __restrict__ H,   // M x 1536
                                               const float* __restrict__ S,            // 8 x 1536
                                               const float* __restrict__ c2,
                                               const float* __restrict__ xg,
                                               float* __restrict__ out){
  __shared__ __align__(16) unsigned short aS[128*40];
  __shared__ __align__(16) unsigned short bS[128*40];
  int bid = blockIdx.x;
  int bm = bid % 3;            // channel tile (3 x 128 = 384)
  int bn = bid / 3;            // pixel tile (256 x 128 = 32768)
  int c0 = bm*128, p0 = bn*128;
  int img = p0 >> 12;
  const float* Simg = S + img*FDIM;
  int tid = threadIdx.x;
  int lane = tid & 63, wid = tid >> 6;
  int wr = wid >> 1, wc = wid & 1;
  int lm = lane & 15, g = lane >> 4;
  int sr = tid & 127, sc = tid >> 7;
  f32x4 acc[4][4];
  #pragma unroll
  for (int i = 0; i < 4; ++i)
    #pragma unroll
    for (int j = 0; j < 4; ++j) acc[i][j] = (f32x4){0.f,0.f,0.f,0.f};

  for (int k0 = 0; k0 < FDIM; k0 += 32){
    __syncthreads();
    const unsigned short* ga = W2T + (size_t)(c0 + sr)*FDIM + k0 + sc*16;
    *(short8*)&aS[sr*40 + sc*16]     = *(const short8*)(ga);
    *(short8*)&aS[sr*40 + sc*16 + 8] = *(const short8*)(ga + 8);
    const unsigned short* gb = H + (size_t)(p0 + sr)*FDIM + k0 + sc*16;
    short8 h0 = *(const short8*)(gb);
    short8 h1 = *(const short8*)(gb + 8);
    const float* sv = Simg + k0 + sc*16;
    short8 o0, o1;
    #pragma unroll
    for (int e = 0; e < 8; ++e){
      o0[e] = (short)bf16_rn(bf2f((unsigned short)h0[e]) * sv[e]);
      o1[e] = (short)bf16_rn(bf2f((unsigned short)h1[e]) * sv[e+8]);
    }
    *(short8*)&bS[sr*40 + sc*16]     = o0;
    *(short8*)&bS[sr*40 + sc*16 + 8] = o1;
    __syncthreads();
    bf16x8 aF[4], bF[4];
    #pragma unroll
    for (int fm = 0; fm < 4; ++fm) aF[fm] = *(const bf16x8*)&aS[(wr*64 + fm*16 + lm)*40 + g*8];
    #pragma unroll
    for (int fn = 0; fn < 4; ++fn) bF[fn] = *(const bf16x8*)&bS[(wc*64 + fn*16 + lm)*40 + g*8];
    #pragma unroll
    for (int fm = 0; fm < 4; ++fm)
      #pragma unroll
      for (int fn = 0; fn < 4; ++fn)
        acc[fm][fn] = __builtin_amdgcn_mfma_f32_16x16x32_bf16(aF[fm], bF[fn], acc[fm][fn], 0, 0, 0);
  }

  int sp0 = p0 & 4095;
  #pragma unroll
  for (int fn = 0; fn < 4; ++fn){
    int pixoff = sp0 + wc*64 + fn*16 + lm;
    #pragma unroll
    for (int fm = 0; fm < 4; ++fm){
      #pragma unroll
      for (int r = 0; r < 4; ++r){
        int c = c0 + wr*64 + fm*16 + g*4 + r;
        size_t addr = ((size_t)img*CDIM + c)*HW + pixoff;
        out[addr] = acc[fm][fn][r] + c2[c] + xg[addr];
      }
    }
  }
}

extern "C" void kernel_launch(void* const* d_in, const int* in_sizes, int n_in,
                              void* d_out, int out_size, void* d_ws, size_t ws_size,
                              hipStream_t stream) {
  const float* x    = (const float*)d_in[0];
  const float* wc   = (const float*)d_in[1];
  const float* kpe  = (const float*)d_in[2];
  const float* lnw  = (const float*)d_in[3];
  const float* lnb  = (const float*)d_in[4];
  const float* w1   = (const float*)d_in[5];
  const float* b1   = (const float*)d_in[6];
  const float* gam  = (const float*)d_in[7];
  const float* beta = (const float*)d_in[8];
  const float* w2   = (const float*)d_in[9];
  const float* b2   = (const float*)d_in[10];
  float* out = (float*)d_out;

  char* ws = (char*)d_ws;
  size_t o = 0;
  auto take = [&](size_t bytes)->char*{
    char* p = ws + o;
    o = (o + bytes + 511) & ~(size_t)511;
    return p;
  };
  // y (conv output, 50.3 MB) aliases d_out: it is fully consumed by k_ln before
  // k_gemm2 writes the real output (gemm2 reads only x/H/S/c2).
  float*          y     = out;
  float*          wfull = (float*)take((size_t)CDIM*2601*4);
  unsigned short* yn    = (unsigned short*)take((size_t)NPIX*CDIM*2);
  unsigned short* H     = (unsigned short*)take((size_t)NPIX*FDIM*2);
  unsigned short* w1T   = (unsigned short*)take((size_t)CDIM*FDIM*2);
  unsigned short* w2T   = (unsigned short*)take((size_t)CDIM*FDIM*2);
  float*          grn   = (float*)take(8*FDIM*4);
  float*          S     = (float*)take(8*FDIM*4);
  float*          c2    = (float*)take(CDIM*4);
  if (o > ws_size) return;   // workspace too small: leave output untouched (visible clean fail)

  k_build_w<<<CDIM, 256, 0, stream>>>(wc, kpe, wfull);
  k_conv_mfma<<<3072, 256, 0, stream>>>(x, wfull, y);
  k_ln<<<NPIX/256, 256, 0, stream>>>(y, lnw, lnb, yn);
  k_w1t<<<(CDIM*FDIM + 255)/256, 256, 0, stream>>>(w1, w1T);
  k_w2t<<<(CDIM*FDIM + 255)/256, 256, 0, stream>>>(w2, w2T);
  k_c2<<<CDIM, 256, 0, stream>>>(w2, beta, b2, c2);
  hipMemsetAsync(grn, 0, 8*FDIM*4, stream);
  k_gemm1<<<(NPIX/128)*(FDIM/128), 256, 0, stream>>>(yn, w1T, b1, H, grn);
  k_grn<<<8, 256, 0, stream>>>(grn, gam, S);
  k_gemm2<<<3*(NPIX/128), 256, 0, stream>>>(w2T, H, S, c2, x, out);
}

// Round 8
// 486.869 us; speedup vs baseline: 2.1304x; 1.0286x over previous
//
#include <hip/hip_runtime.h>

#define CDIM 384
#define FDIM 1536
#define KK 51
#define RAD 25
#define NPIX 32768     // B*H*W
#define HW 4096        // 64*64

#define CSTR 136       // shifted-copy stride (elements)
#define OSTR 68        // out accumulator row stride (f32 words)

typedef float  f32x4  __attribute__((ext_vector_type(4)));
typedef short  short8 __attribute__((ext_vector_type(8)));
typedef __bf16 bf16x8 __attribute__((ext_vector_type(8)));
typedef unsigned short us4 __attribute__((ext_vector_type(4)));

// per-axis peripheral index: coords {0,1,2,4,8,16,25}, signed list P=13
__device__ __constant__ int AXIS[51] = {
  0,
  1,1,1,1,1,1,1,1,1,
  2,2,2,2,2,2,2,2,
  3,3,3,3,
  4,4,
  5,
  6,
  7,
  8,8,
  9,9,9,9,
  10,10,10,10,10,10,10,10,
  11,11,11,11,11,11,11,11,11,
  12
};

__device__ __forceinline__ unsigned short bf16_rn(float x){
  union { float f; unsigned u; } v; v.f = x;
  unsigned r = v.u + 0x7FFFu + ((v.u >> 16) & 1u);
  return (unsigned short)(r >> 16);
}
__device__ __forceinline__ float bf2f(unsigned short h){
  union { unsigned u; float f; } v; v.u = ((unsigned)h) << 16; return v.f;
}

// ---------------- K0: expand per-channel kernel: w[c,i,j] = wc[c, cell(i,j)] + kpe[i,j]
__global__ __launch_bounds__(256) void k_build_w(const float* __restrict__ wc,
                                                 const float* __restrict__ kpe,
                                                 float* __restrict__ wfull){
  int c = blockIdx.x;
  const float* wcc = wc + c*169;
  float* wo = wfull + (size_t)c*2601;
  for (int idx = threadIdx.x; idx < 2601; idx += 256){
    int i = idx / 51, j = idx - i*51;
    wo[idx] = wcc[AXIS[i]*13 + AXIS[j]] + kpe[idx];
  }
}

// ---------------- K1: depthwise conv 51x51 via MFMA row-Toeplitz scatter,
// 4-row alignment-class batching + async-STAGE split (T14):
// next row's global loads issue at phase START (regs), the LDS write of the
// staged row happens AFTER the MFMA/RMW section, so VMEM latency hides under
// compute. One block = one (b,c) image, 16 phases.
__global__ __launch_bounds__(256) void k_conv_mfma(const float* __restrict__ x,
                                                   const float* __restrict__ wfull,
                                                   float* __restrict__ y){
  __shared__ __align__(16) float outb[64*OSTR];              // 17408 B accumulator
  __shared__ __align__(16) unsigned short bufs[2][4][1088];  // 17408 B row copies
  int img = blockIdx.x;                 // b*384 + c
  int ch  = img % CDIM;
  const float* xim = x + (size_t)img*HW;
  const float* wch = wfull + (size_t)ch*2601;
  int tid = threadIdx.x;
  int lane = tid & 63, wid = tid >> 6;  // wid = q-tile
  int li = lane & 15, g = lane >> 4;
  int t0 = (lane & 31) << 2;            // us4 position within a copy
  int c0 = lane >> 5;                   // base copy index (it adds 2 per step)

  // zero accumulator (64*68 = 4352 words = 1088 f32x4, exact)
  for (int i = tid; i < 1088; i += 256)
    *(f32x4*)&outb[i*4] = (f32x4){0.f,0.f,0.f,0.f};

  // B fragments (w rows) straight from global, bf16, zero-padded:
  // lane li holds w[i = nt*16+li, j = kt*32 + g*8 + e]
  bf16x8 Bf[4][2];
  #pragma unroll
  for (int nt = 0; nt < 4; ++nt){
    int i = nt*16 + li;
    #pragma unroll
    for (int kt = 0; kt < 2; ++kt){
      union { bf16x8 v; unsigned short u[8]; } tmp;
      #pragma unroll
      for (int e = 0; e < 8; ++e){
        int j = kt*32 + g*8 + e;
        float v = (i < 51 && j < 51) ? wch[i*51 + j] : 0.f;
        tmp.u[e] = bf16_rn(v);
      }
      Bf[nt][kt] = tmp.v;
    }
  }

  // stage phase 0 row (16*wid) directly (prologue only)
  {
    const float* xr = xim + (16*wid)*64;
    #pragma unroll
    for (int it = 0; it < 4; ++it){
      int c = c0 + 2*it;
      us4 o;
      #pragma unroll
      for (int e = 0; e < 4; ++e){
        int xi = t0 + e + c - 25;
        float v = (xi >= 0 && xi < 64) ? xr[xi] : 0.f;
        o[e] = bf16_rn(v);
      }
      *(us4*)&bufs[0][wid][c*CSTR + t0] = o;
    }
  }
  __syncthreads();

  #pragma unroll 1
  for (int ph = 0; ph < 16; ++ph){
    // (1) issue next row's global loads NOW (clamped addr; masked at use)
    float pf[16];
    if (ph + 1 < 16){
      const float* xr = xim + (ph + 1 + 16*wid)*64;
      #pragma unroll
      for (int it = 0; it < 4; ++it){
        int c = c0 + 2*it;
        #pragma unroll
        for (int e = 0; e < 4; ++e){
          int xi = t0 + e + c - 25;
          int xc = min(max(xi, 0), 63);
          pf[it*4 + e] = xr[xc];
        }
      }
    }

    // (2) A fragments for the 4 rows of this phase:
    // lane li holds x[r, (wid*16+li) + (kt*32+g*8+e) - 25]
    bf16x8 Af[4][2];
    #pragma unroll
    for (int s = 0; s < 4; ++s){
      const unsigned short* bb = &bufs[ph & 1][s][0];
      #pragma unroll
      for (int kt = 0; kt < 2; ++kt){
        int u0 = wid*16 + kt*32 + g*8 + li;
        int c  = li & 7;
        Af[s][kt] = *(const bf16x8*)&bb[c*CSTR + (u0 - c)];
      }
    }

    // (3) 6 alignment classes d = s - nt in [-2, 3]
    #pragma unroll
    for (int dd = 0; dd < 6; ++dd){
      int d = dd - 2;
      int pmax = ph + 25 + 16*d;
      if (pmax < 0 || pmax > 78) continue;     // no valid lane (wave-uniform)
      f32x4 V = {0.f,0.f,0.f,0.f};
      #pragma unroll
      for (int s = 0; s < 4; ++s){
        int nt = s - d;
        if (nt < 0 || nt > 3) continue;        // compile-time after unroll
        V = __builtin_amdgcn_mfma_f32_16x16x32_bf16(Af[s][0], Bf[nt][0], V, 0, 0, 0);
        V = __builtin_amdgcn_mfma_f32_16x16x32_bf16(Af[s][1], Bf[nt][1], V, 0, 0, 0);
      }
      // lane holds V[q = wid*16 + g*4 + reg] for out row p = pmax - li
      int p = pmax - li;
      if (p >= 0 && p < 64){
        float* oa = &outb[p*OSTR + wid*16 + g*4];
        f32x4 old = *(const f32x4*)oa;
        *(f32x4*)oa = old + V;
      }
    }

    // (4) convert + LDS-write the prefetched row into the other buffer
    if (ph + 1 < 16){
      unsigned short* dst = &bufs[(ph + 1) & 1][wid][0];
      #pragma unroll
      for (int it = 0; it < 4; ++it){
        int c = c0 + 2*it;
        us4 o;
        #pragma unroll
        for (int e = 0; e < 4; ++e){
          int xi = t0 + e + c - 25;
          float v = (xi >= 0 && xi < 64) ? pf[it*4 + e] : 0.f;
          o[e] = bf16_rn(v);
        }
        *(us4*)&dst[c*CSTR + t0] = o;
      }
    }
    __syncthreads();
  }

  // epilogue: out -> global (coalesced f32x4)
  float* yo = y + (size_t)img*HW;
  #pragma unroll
  for (int k = 0; k < 4; ++k){
    int pix = k*1024 + tid*4;
    int p = pix >> 6, q = pix & 63;
    *(f32x4*)(yo + pix) = *(const f32x4*)&outb[p*OSTR + q];
  }
}

// ---------------- K2: LayerNorm over C (NCHW f32 -> NHWC bf16), LDS transpose for coalesced writes
__global__ __launch_bounds__(256) void k_ln(const float* __restrict__ y,
                                            const float* __restrict__ lnw,
                                            const float* __restrict__ lnb,
                                            unsigned short* __restrict__ yn){
  __shared__ unsigned short tile[4][64*66];
  int tid = threadIdx.x, lane = tid & 63, wid = tid >> 6;
  int pg = blockIdx.x*256 + wid*64 + lane;        // pixel id
  int b = pg >> 12, sp = pg & 4095;
  const float* yb = y + (size_t)b*CDIM*HW + sp;
  float sum = 0.f, sq = 0.f;
  for (int c = 0; c < CDIM; ++c){
    float v = yb[(size_t)c*HW];
    sum += v; sq += v*v;
  }
  float mu   = sum * (1.f/CDIM);
  float var  = sq  * (1.f/CDIM) - mu*mu;
  float rstd = rsqrtf(var + 1e-6f);
  unsigned short* tl = tile[wid];
  int pixbase = blockIdx.x*256 + wid*64;
  for (int c0 = 0; c0 < CDIM; c0 += 64){
    #pragma unroll 4
    for (int cc = 0; cc < 64; ++cc){
      int c = c0 + cc;
      float v = (yb[(size_t)c*HW] - mu) * rstd * lnw[c] + lnb[c];
      tl[cc*66 + lane] = bf16_rn(v);
    }
    // same-wave LDS RAW: compiler inserts waitcnt
    for (int p = 0; p < 64; ++p){
      yn[(size_t)(pixbase + p)*CDIM + c0 + lane] = tl[lane*66 + p];
    }
  }
}

// ---------------- K4/K5: weight transposes to bf16
__global__ __launch_bounds__(256) void k_w1t(const float* __restrict__ w1, unsigned short* __restrict__ w1T){
  int idx = blockIdx.x*256 + threadIdx.x;
  if (idx < CDIM*FDIM){ int c = idx / FDIM, f = idx - c*FDIM; w1T[(size_t)f*CDIM + c] = bf16_rn(w1[idx]); }
}
__global__ __launch_bounds__(256) void k_w2t(const float* __restrict__ w2, unsigned short* __restrict__ w2T){
  int idx = blockIdx.x*256 + threadIdx.x;
  if (idx < CDIM*FDIM){ int f = idx / CDIM, c = idx - f*CDIM; w2T[(size_t)c*FDIM + f] = bf16_rn(w2[idx]); }
}

// ---------------- K8: c2[c] = b2[c] + sum_f beta[f]*w2[f,c]  (block per c, parallel over f)
__global__ __launch_bounds__(256) void k_c2(const float* __restrict__ w2,
                                            const float* __restrict__ beta,
                                            const float* __restrict__ b2,
                                            float* __restrict__ c2){
  int c = blockIdx.x;
  __shared__ float red[256];
  float s = 0.f;
  for (int f = threadIdx.x; f < FDIM; f += 256) s += beta[f] * w2[(size_t)f*CDIM + c];
  red[threadIdx.x] = s;
  __syncthreads();
  for (int t = 128; t > 0; t >>= 1){
    if (threadIdx.x < t) red[threadIdx.x] += red[threadIdx.x + t];
    __syncthreads();
  }
  if (threadIdx.x == 0) c2[c] = red[0] + b2[c];
}

// ---------------- K6: GEMM1 persistent-A: block = 64 pixels x all 1536 f, K=384 resident in LDS.
// Eliminates the 12x re-read of yn. + b1 + exact GELU -> H bf16; GRN partial sums.
__global__ __launch_bounds__(256) void k_gemm1p(const unsigned short* __restrict__ A,   // yn M x 384
                                                const unsigned short* __restrict__ BT,  // w1T 1536 x 384
                                                const float* __restrict__ b1,
                                                unsigned short* __restrict__ H,         // M x 1536
                                                float* __restrict__ grn){               // 8 x 1536
  __shared__ __align__(16) unsigned short pan[64*392];   // 49.1 KB A panel (row stride 392)
  __shared__ __align__(16) unsigned short bS[128*40];    // 10 KB B tile
  int m0 = blockIdx.x * 64;
  int img = m0 >> 12;
  int tid = threadIdx.x;
  int lane = tid & 63, wid = tid >> 6;
  int wr = wid >> 1, wc = wid & 1;     // wave tile: 32 pixels x 64 f
  int lm = lane & 15, g = lane >> 4;
  int sr = tid & 127, sc = tid >> 7;   // B staging coords

  // stage A panel once: 64 rows x 384 el (48 chunks of 8)
  #pragma unroll
  for (int t = 0; t < 12; ++t){
    int idx = tid + 256*t;             // 0..3071 = 64*48
    int row = idx / 48, ch = idx - row*48;
    *(short8*)&pan[row*392 + ch*8] = *(const short8*)(A + (size_t)(m0 + row)*CDIM + ch*8);
  }

  #pragma unroll 1
  for (int ft = 0; ft < 12; ++ft){
    int n0 = ft*128;
    f32x4 acc[2][4];
    #pragma unroll
    for (int i = 0; i < 2; ++i)
      #pragma unroll
      for (int j = 0; j < 4; ++j) acc[i][j] = (f32x4){0.f,0.f,0.f,0.f};

    for (int k0 = 0; k0 < CDIM; k0 += 32){
      __syncthreads();   // protects bS (and, first iter, the A panel)
      const unsigned short* gb = BT + (size_t)(n0 + sr)*CDIM + k0 + sc*16;
      *(short8*)&bS[sr*40 + sc*16]     = *(const short8*)(gb);
      *(short8*)&bS[sr*40 + sc*16 + 8] = *(const short8*)(gb + 8);
      __syncthreads();
      bf16x8 aF[2], bF[4];
      #pragma unroll
      for (int fm = 0; fm < 2; ++fm) aF[fm] = *(const bf16x8*)&pan[(wr*32 + fm*16 + lm)*392 + k0 + g*8];
      #pragma unroll
      for (int fn = 0; fn < 4; ++fn) bF[fn] = *(const bf16x8*)&bS[(wc*64 + fn*16 + lm)*40 + g*8];
      #pragma unroll
      for (int fm = 0; fm < 2; ++fm)
        #pragma unroll
        for (int fn = 0; fn < 4; ++fn)
          acc[fm][fn] = __builtin_amdgcn_mfma_f32_16x16x32_bf16(aF[fm], bF[fn], acc[fm][fn], 0, 0, 0);
    }

    // epilogue for this f-tile
    float psum[4] = {0.f,0.f,0.f,0.f};
    #pragma unroll
    for (int fn = 0; fn < 4; ++fn){
      int n = n0 + wc*64 + fn*16 + lm;
      float bias = b1[n];
      #pragma unroll
      for (int fm = 0; fm < 2; ++fm){
        int mb = m0 + wr*32 + fm*16 + g*4;
        #pragma unroll
        for (int r = 0; r < 4; ++r){
          float v = acc[fm][fn][r] + bias;
          v = 0.5f * v * (1.f + erff(v * 0.70710678118654752f));   // exact GELU
          H[(size_t)(mb + r)*FDIM + n] = bf16_rn(v);
          psum[fn] += v*v;
        }
      }
    }
    #pragma unroll
    for (int fn = 0; fn < 4; ++fn){
      float v = psum[fn];
      v += __shfl_xor(v, 16);
      v += __shfl_xor(v, 32);
      if (g == 0){
        atomicAdd(&grn[img*FDIM + n0 + wc*64 + fn*16 + lm], v);
      }
    }
  }
}

// ---------------- K7: GRN finalize -> S[n,f] = 1 + gamma[f]*nx
__global__ __launch_bounds__(256) void k_grn(const float* __restrict__ grn,
                                             const float* __restrict__ gamma,
                                             float* __restrict__ S){
  int n = blockIdx.x;
  const float* g = grn + n*FDIM;
  __shared__ float red[256];
  float p = 0.f;
  for (int f = threadIdx.x; f < FDIM; f += 256) p += sqrtf(g[f]);
  red[threadIdx.x] = p;
  __syncthreads();
  for (int s = 128; s > 0; s >>= 1){
    if (threadIdx.x < s) red[threadIdx.x] += red[threadIdx.x + s];
    __syncthreads();
  }
  float mean = red[0] * (1.f/FDIM);
  float inv = 1.f/(mean + 1e-6f);
  for (int f = threadIdx.x; f < FDIM; f += 256){
    float nx = sqrtf(g[f]) * inv;
    S[n*FDIM + f] = 1.f + gamma[f]*nx;
  }
}

// ---------------- K9: GEMM2: out[c,pix] = sum_f w2T[c,f]*(H[pix,f]*S[img,f]) + c2[c] + x  (M-dim=c, N-dim=pix)
__global__ __launch_bounds__(256) void k_gemm2(const unsigned short* __restrict__ W2T, // 384 x 1536
                                               const unsigned short* __restrict__ H,   // M x 1536
                                               const float* __restrict__ S,            // 8 x 1536
                                               const float* __restrict__ c2,
                                               const float* __restrict__ xg,
                                               float* __restrict__ out){
  __shared__ __align__(16) unsigned short aS[128*40];
  __shared__ __align__(16) unsigned short bS[128*40];
  int bid = blockIdx.x;
  int bm = bid % 3;            // channel tile (3 x 128 = 384)
  int bn = bid / 3;            // pixel tile (256 x 128 = 32768)
  int c0 = bm*128, p0 = bn*128;
  int img = p0 >> 12;
  const float* Simg = S + img*FDIM;
  int tid = threadIdx.x;
  int lane = tid & 63, wid = tid >> 6;
  int wr = wid >> 1, wc = wid & 1;
  int lm = lane & 15, g = lane >> 4;
  int sr = tid & 127, sc = tid >> 7;
  f32x4 acc[4][4];
  #pragma unroll
  for (int i = 0; i < 4; ++i)
    #pragma unroll
    for (int j = 0; j < 4; ++j) acc[i][j] = (f32x4){0.f,0.f,0.f,0.f};

  for (int k0 = 0; k0 < FDIM; k0 += 32){
    __syncthreads();
    const unsigned short* ga = W2T + (size_t)(c0 + sr)*FDIM + k0 + sc*16;
    *(short8*)&aS[sr*40 + sc*16]     = *(const short8*)(ga);
    *(short8*)&aS[sr*40 + sc*16 + 8] = *(const short8*)(ga + 8);
    const unsigned short* gb = H + (size_t)(p0 + sr)*FDIM + k0 + sc*16;
    short8 h0 = *(const short8*)(gb);
    short8 h1 = *(const short8*)(gb + 8);
    const float* sv = Simg + k0 + sc*16;
    short8 o0, o1;
    #pragma unroll
    for (int e = 0; e < 8; ++e){
      o0[e] = (short)bf16_rn(bf2f((unsigned short)h0[e]) * sv[e]);
      o1[e] = (short)bf16_rn(bf2f((unsigned short)h1[e]) * sv[e+8]);
    }
    *(short8*)&bS[sr*40 + sc*16]     = o0;
    *(short8*)&bS[sr*40 + sc*16 + 8] = o1;
    __syncthreads();
    bf16x8 aF[4], bF[4];
    #pragma unroll
    for (int fm = 0; fm < 4; ++fm) aF[fm] = *(const bf16x8*)&aS[(wr*64 + fm*16 + lm)*40 + g*8];
    #pragma unroll
    for (int fn = 0; fn < 4; ++fn) bF[fn] = *(const bf16x8*)&bS[(wc*64 + fn*16 + lm)*40 + g*8];
    #pragma unroll
    for (int fm = 0; fm < 4; ++fm)
      #pragma unroll
      for (int fn = 0; fn < 4; ++fn)
        acc[fm][fn] = __builtin_amdgcn_mfma_f32_16x16x32_bf16(aF[fm], bF[fn], acc[fm][fn], 0, 0, 0);
  }

  int sp0 = p0 & 4095;
  #pragma unroll
  for (int fn = 0; fn < 4; ++fn){
    int pixoff = sp0 + wc*64 + fn*16 + lm;
    #pragma unroll
    for (int fm = 0; fm < 4; ++fm){
      #pragma unroll
      for (int r = 0; r < 4; ++r){
        int c = c0 + wr*64 + fm*16 + g*4 + r;
        size_t addr = ((size_t)img*CDIM + c)*HW + pixoff;
        out[addr] = acc[fm][fn][r] + c2[c] + xg[addr];
      }
    }
  }
}

extern "C" void kernel_launch(void* const* d_in, const int* in_sizes, int n_in,
                              void* d_out, int out_size, void* d_ws, size_t ws_size,
                              hipStream_t stream) {
  const float* x    = (const float*)d_in[0];
  const float* wc   = (const float*)d_in[1];
  const float* kpe  = (const float*)d_in[2];
  const float* lnw  = (const float*)d_in[3];
  const float* lnb  = (const float*)d_in[4];
  const float* w1   = (const float*)d_in[5];
  const float* b1   = (const float*)d_in[6];
  const float* gam  = (const float*)d_in[7];
  const float* beta = (const float*)d_in[8];
  const float* w2   = (const float*)d_in[9];
  const float* b2   = (const float*)d_in[10];
  float* out = (float*)d_out;

  char* ws = (char*)d_ws;
  size_t o = 0;
  auto take = [&](size_t bytes)->char*{
    char* p = ws + o;
    o = (o + bytes + 511) & ~(size_t)511;
    return p;
  };
  // y (conv output, 50.3 MB) aliases d_out: it is fully consumed by k_ln before
  // k_gemm2 writes the real output (gemm2 reads only x/H/S/c2).
  float*          y     = out;
  float*          wfull = (float*)take((size_t)CDIM*2601*4);
  unsigned short* yn    = (unsigned short*)take((size_t)NPIX*CDIM*2);
  unsigned short* H     = (unsigned short*)take((size_t)NPIX*FDIM*2);
  unsigned short* w1T   = (unsigned short*)take((size_t)CDIM*FDIM*2);
  unsigned short* w2T   = (unsigned short*)take((size_t)CDIM*FDIM*2);
  float*          grn   = (float*)take(8*FDIM*4);
  float*          S     = (float*)take(8*FDIM*4);
  float*          c2    = (float*)take(CDIM*4);
  if (o > ws_size) return;   // workspace too small: leave output untouched (visible clean fail)

  k_build_w<<<CDIM, 256, 0, stream>>>(wc, kpe, wfull);
  k_conv_mfma<<<3072, 256, 0, stream>>>(x, wfull, y);
  k_ln<<<NPIX/256, 256, 0, stream>>>(y, lnw, lnb, yn);
  k_w1t<<<(CDIM*FDIM + 255)/256, 256, 0, stream>>>(w1, w1T);
  k_w2t<<<(CDIM*FDIM + 255)/256, 256, 0, stream>>>(w2, w2T);
  k_c2<<<CDIM, 256, 0, stream>>>(w2, beta, b2, c2);
  hipMemsetAsync(grn, 0, 8*FDIM*4, stream);
  k_gemm1p<<<NPIX/64, 256, 0, stream>>>(yn, w1T, b1, H, grn);
  k_grn<<<8, 256, 0, stream>>>(grn, gam, S);
  k_gemm2<<<3*(NPIX/128), 256, 0, stream>>>(w2T, H, S, c2, x, out);
}

// Round 9
// 470.024 us; speedup vs baseline: 2.2068x; 1.0358x over previous
//
#include <hip/hip_runtime.h>

#define CDIM 384
#define FDIM 1536
#define KK 51
#define RAD 25
#define NPIX 32768     // B*H*W
#define HW 4096        // 64*64

#define CSTR 136       // shifted-copy stride (elements)
#define OSTR 68        // out accumulator row stride (f32 words)

typedef float  f32x4  __attribute__((ext_vector_type(4)));
typedef short  short8 __attribute__((ext_vector_type(8)));
typedef __bf16 bf16x8 __attribute__((ext_vector_type(8)));
typedef unsigned short us4 __attribute__((ext_vector_type(4)));

// per-axis peripheral index: coords {0,1,2,4,8,16,25}, signed list P=13
__device__ __constant__ int AXIS[51] = {
  0,
  1,1,1,1,1,1,1,1,1,
  2,2,2,2,2,2,2,2,
  3,3,3,3,
  4,4,
  5,
  6,
  7,
  8,8,
  9,9,9,9,
  10,10,10,10,10,10,10,10,
  11,11,11,11,11,11,11,11,11,
  12
};

__device__ __forceinline__ unsigned short f2bf(float x){
  __bf16 h = (__bf16)x;                 // RNE; compiler emits cvt_pk when paired
  return __builtin_bit_cast(unsigned short, h);
}
__device__ __forceinline__ float bf2f(unsigned short h){
  union { unsigned u; float f; } v; v.u = ((unsigned)h) << 16; return v.f;
}

// ---------------- K0: expand per-channel kernel: w[c,i,j] = wc[c, cell(i,j)] + kpe[i,j]
__global__ __launch_bounds__(256) void k_build_w(const float* __restrict__ wc,
                                                 const float* __restrict__ kpe,
                                                 float* __restrict__ wfull){
  int c = blockIdx.x;
  const float* wcc = wc + c*169;
  float* wo = wfull + (size_t)c*2601;
  for (int idx = threadIdx.x; idx < 2601; idx += 256){
    int i = idx / 51, j = idx - i*51;
    wo[idx] = wcc[AXIS[i]*13 + AXIS[j]] + kpe[idx];
  }
}

// ---------------- K1: depthwise conv 51x51 via MFMA row-Toeplitz scatter,
// 4-row alignment-class batching + async-STAGE split. One block = one (b,c) image.
__global__ __launch_bounds__(256) void k_conv_mfma(const float* __restrict__ x,
                                                   const float* __restrict__ wfull,
                                                   float* __restrict__ y){
  __shared__ __align__(16) float outb[64*OSTR];              // 17408 B accumulator
  __shared__ __align__(16) unsigned short bufs[2][4][1088];  // 17408 B row copies
  int img = blockIdx.x;                 // b*384 + c
  int ch  = img % CDIM;
  const float* xim = x + (size_t)img*HW;
  const float* wch = wfull + (size_t)ch*2601;
  int tid = threadIdx.x;
  int lane = tid & 63, wid = tid >> 6;  // wid = q-tile
  int li = lane & 15, g = lane >> 4;
  int t0 = (lane & 31) << 2;            // us4 position within a copy
  int c0 = lane >> 5;                   // base copy index (it adds 2 per step)

  // zero accumulator
  for (int i = tid; i < 1088; i += 256)
    *(f32x4*)&outb[i*4] = (f32x4){0.f,0.f,0.f,0.f};

  // B fragments (w rows) straight from global, bf16, zero-padded
  bf16x8 Bf[4][2];
  #pragma unroll
  for (int nt = 0; nt < 4; ++nt){
    int i = nt*16 + li;
    #pragma unroll
    for (int kt = 0; kt < 2; ++kt){
      union { bf16x8 v; unsigned short u[8]; } tmp;
      #pragma unroll
      for (int e = 0; e < 8; ++e){
        int j = kt*32 + g*8 + e;
        float v = (i < 51 && j < 51) ? wch[i*51 + j] : 0.f;
        tmp.u[e] = f2bf(v);
      }
      Bf[nt][kt] = tmp.v;
    }
  }

  // stage phase 0 row (16*wid)
  {
    const float* xr = xim + (16*wid)*64;
    #pragma unroll
    for (int it = 0; it < 4; ++it){
      int c = c0 + 2*it;
      us4 o;
      #pragma unroll
      for (int e = 0; e < 4; ++e){
        int xi = t0 + e + c - 25;
        float v = (xi >= 0 && xi < 64) ? xr[xi] : 0.f;
        o[e] = f2bf(v);
      }
      *(us4*)&bufs[0][wid][c*CSTR + t0] = o;
    }
  }
  __syncthreads();

  #pragma unroll 1
  for (int ph = 0; ph < 16; ++ph){
    // (1) issue next row's global loads NOW (clamped addr; masked at use)
    float pf[16];
    if (ph + 1 < 16){
      const float* xr = xim + (ph + 1 + 16*wid)*64;
      #pragma unroll
      for (int it = 0; it < 4; ++it){
        int c = c0 + 2*it;
        #pragma unroll
        for (int e = 0; e < 4; ++e){
          int xi = t0 + e + c - 25;
          int xc = min(max(xi, 0), 63);
          pf[it*4 + e] = xr[xc];
        }
      }
    }

    // (2) A fragments for the 4 rows of this phase
    bf16x8 Af[4][2];
    #pragma unroll
    for (int s = 0; s < 4; ++s){
      const unsigned short* bb = &bufs[ph & 1][s][0];
      #pragma unroll
      for (int kt = 0; kt < 2; ++kt){
        int u0 = wid*16 + kt*32 + g*8 + li;
        int c  = li & 7;
        Af[s][kt] = *(const bf16x8*)&bb[c*CSTR + (u0 - c)];
      }
    }

    // (3) 6 alignment classes d = s - nt in [-2, 3]
    #pragma unroll
    for (int dd = 0; dd < 6; ++dd){
      int d = dd - 2;
      int pmax = ph + 25 + 16*d;
      if (pmax < 0 || pmax > 78) continue;     // wave-uniform skip
      f32x4 V = {0.f,0.f,0.f,0.f};
      #pragma unroll
      for (int s = 0; s < 4; ++s){
        int nt = s - d;
        if (nt < 0 || nt > 3) continue;        // compile-time after unroll
        V = __builtin_amdgcn_mfma_f32_16x16x32_bf16(Af[s][0], Bf[nt][0], V, 0, 0, 0);
        V = __builtin_amdgcn_mfma_f32_16x16x32_bf16(Af[s][1], Bf[nt][1], V, 0, 0, 0);
      }
      int p = pmax - li;
      if (p >= 0 && p < 64){
        float* oa = &outb[p*OSTR + wid*16 + g*4];
        f32x4 old = *(const f32x4*)oa;
        *(f32x4*)oa = old + V;
      }
    }

    // (4) convert + LDS-write the prefetched row into the other buffer
    if (ph + 1 < 16){
      unsigned short* dst = &bufs[(ph + 1) & 1][wid][0];
      #pragma unroll
      for (int it = 0; it < 4; ++it){
        int c = c0 + 2*it;
        us4 o;
        #pragma unroll
        for (int e = 0; e < 4; ++e){
          int xi = t0 + e + c - 25;
          float v = (xi >= 0 && xi < 64) ? pf[it*4 + e] : 0.f;
          o[e] = f2bf(v);
        }
        *(us4*)&dst[c*CSTR + t0] = o;
      }
    }
    __syncthreads();
  }

  // epilogue: out -> global (coalesced f32x4)
  float* yo = y + (size_t)img*HW;
  #pragma unroll
  for (int k = 0; k < 4; ++k){
    int pix = k*1024 + tid*4;
    int p = pix >> 6, q = pix & 63;
    *(f32x4*)(yo + pix) = *(const f32x4*)&outb[p*OSTR + q];
  }
}

// ---------------- K2: LayerNorm (NCHW f32 -> NHWC bf16). 512 blocks x 64 pixels.
// Wave w owns channel quarter [96w, 96w+96). Coalesced loads (lane=pixel),
// cross-wave stat combine in LDS, conflict-free transpose, coalesced writes.
__global__ __launch_bounds__(256) void k_ln(const float* __restrict__ y,
                                            const float* __restrict__ lnw,
                                            const float* __restrict__ lnb,
                                            unsigned short* __restrict__ yn){
  __shared__ float sred[2][4][64];
  __shared__ unsigned short tile[384*66];   // [c][pixel] padded stride 66
  int tid = threadIdx.x, lane = tid & 63, w = tid >> 6;
  int pg0 = blockIdx.x * 64;            // 64 pixels per block (same image)
  int b = pg0 >> 12, sp0 = pg0 & 4095;
  const float* yb = y + (size_t)b*CDIM*HW + sp0 + lane;  // lane = pixel
  int cbase = w * 96;
  float sum = 0.f, sq = 0.f;
  for (int cc = 0; cc < 96; ++cc){
    float v = yb[(size_t)(cbase + cc)*HW];
    sum += v; sq += v*v;
  }
  sred[0][w][lane] = sum; sred[1][w][lane] = sq;
  __syncthreads();
  float ts = 0.f, tq = 0.f;
  #pragma unroll
  for (int u = 0; u < 4; ++u){ ts += sred[0][u][lane]; tq += sred[1][u][lane]; }
  float mu   = ts * (1.f/CDIM);
  float var  = tq * (1.f/CDIM) - mu*mu;
  float rstd = rsqrtf(var + 1e-6f);
  for (int cc = 0; cc < 96; ++cc){
    int c = cbase + cc;
    float v = (yb[(size_t)c*HW] - mu) * rstd * lnw[c] + lnb[c];
    tile[c*66 + lane] = f2bf(v);
  }
  __syncthreads();
  // wave w writes pixels [16w, 16w+16); lane varies c -> coalesced 128B stores
  for (int pp = 0; pp < 16; ++pp){
    int p = w*16 + pp;
    size_t orow = (size_t)(pg0 + p)*CDIM;
    #pragma unroll
    for (int chk = 0; chk < 6; ++chk){
      yn[orow + chk*64 + lane] = tile[(chk*64 + lane)*66 + p];
    }
  }
}

// ---------------- K4: tiled transpose + cvt: dst[c][r] = bf16(src[r][c]), src R x C
__global__ __launch_bounds__(256) void k_wt(const float* __restrict__ src,
                                            unsigned short* __restrict__ dst,
                                            int R, int C){
  __shared__ float tile[64][65];
  int tc = blockIdx.x % (C >> 6);       // column-tile
  int tr = blockIdx.x / (C >> 6);       // row-tile
  int r0 = tr*64, c0 = tc*64;
  int lane = threadIdx.x & 63, q = threadIdx.x >> 6;
  #pragma unroll
  for (int it = 0; it < 16; ++it){
    int r = it*4 + q;
    tile[r][lane] = src[(size_t)(r0 + r)*C + c0 + lane];
  }
  __syncthreads();
  #pragma unroll
  for (int it = 0; it < 16; ++it){
    int c = it*4 + q;
    dst[(size_t)(c0 + c)*R + r0 + lane] = f2bf(tile[lane][c]);
  }
}

// ---------------- K8: c2[c] = b2[c] + sum_f beta[f]*w2[f,c]  (block per c)
__global__ __launch_bounds__(256) void k_c2(const float* __restrict__ w2,
                                            const float* __restrict__ beta,
                                            const float* __restrict__ b2,
                                            float* __restrict__ c2){
  int c = blockIdx.x;
  __shared__ float red[256];
  float s = 0.f;
  for (int f = threadIdx.x; f < FDIM; f += 256) s += beta[f] * w2[(size_t)f*CDIM + c];
  red[threadIdx.x] = s;
  __syncthreads();
  for (int t = 128; t > 0; t >>= 1){
    if (threadIdx.x < t) red[threadIdx.x] += red[threadIdx.x + t];
    __syncthreads();
  }
  if (threadIdx.x == 0) c2[c] = red[0] + b2[c];
}

// ---------------- K6: GEMM1 persistent-A + B-prefetch. Block = 64 pixels x 1536 f.
__global__ __launch_bounds__(256) void k_gemm1p(const unsigned short* __restrict__ A,   // yn M x 384
                                                const unsigned short* __restrict__ BT,  // w1T 1536 x 384
                                                const float* __restrict__ b1,
                                                unsigned short* __restrict__ H,         // M x 1536
                                                float* __restrict__ grn){               // 8 x 1536
  __shared__ __align__(16) unsigned short pan[64*392];   // 49.1 KB A panel
  __shared__ __align__(16) unsigned short bS[128*40];    // 10 KB B tile
  int m0 = blockIdx.x * 64;
  int img = m0 >> 12;
  int tid = threadIdx.x;
  int lane = tid & 63, wid = tid >> 6;
  int wr = wid >> 1, wc = wid & 1;     // wave tile: 32 pixels x 64 f
  int lm = lane & 15, g = lane >> 4;
  int sr = tid & 127, sc = tid >> 7;   // B staging coords

  // stage A panel once
  #pragma unroll
  for (int t = 0; t < 12; ++t){
    int idx = tid + 256*t;             // 0..3071 = 64*48
    int row = idx / 48, ch = idx - row*48;
    *(short8*)&pan[row*392 + ch*8] = *(const short8*)(A + (size_t)(m0 + row)*CDIM + ch*8);
  }

  // prologue loads for (ft=0, k=0)
  short8 r0, r1;
  {
    const unsigned short* gb = BT + (size_t)sr*CDIM + sc*16;
    r0 = *(const short8*)(gb);
    r1 = *(const short8*)(gb + 8);
  }

  #pragma unroll 1
  for (int ft = 0; ft < 12; ++ft){
    int n0 = ft*128;
    f32x4 acc[2][4];
    #pragma unroll
    for (int i = 0; i < 2; ++i)
      #pragma unroll
      for (int j = 0; j < 4; ++j) acc[i][j] = (f32x4){0.f,0.f,0.f,0.f};

    #pragma unroll 1
    for (int ks = 0; ks < 12; ++ks){
      int k0 = ks*32;
      __syncthreads();                 // reads of bS (prev iter) + pan staging done
      *(short8*)&bS[sr*40 + sc*16]     = r0;
      *(short8*)&bS[sr*40 + sc*16 + 8] = r1;
      __syncthreads();
      // issue next-step loads; latency hides under ds_read + MFMA
      if (!(ft == 11 && ks == 11)){
        int nft = (ks == 11) ? ft + 1 : ft;
        int nk  = (ks == 11) ? 0 : k0 + 32;
        const unsigned short* gb = BT + (size_t)(nft*128 + sr)*CDIM + nk + sc*16;
        r0 = *(const short8*)(gb);
        r1 = *(const short8*)(gb + 8);
      }
      bf16x8 aF[2], bF[4];
      #pragma unroll
      for (int fm = 0; fm < 2; ++fm) aF[fm] = *(const bf16x8*)&pan[(wr*32 + fm*16 + lm)*392 + k0 + g*8];
      #pragma unroll
      for (int fn = 0; fn < 4; ++fn) bF[fn] = *(const bf16x8*)&bS[(wc*64 + fn*16 + lm)*40 + g*8];
      #pragma unroll
      for (int fm = 0; fm < 2; ++fm)
        #pragma unroll
        for (int fn = 0; fn < 4; ++fn)
          acc[fm][fn] = __builtin_amdgcn_mfma_f32_16x16x32_bf16(aF[fm], bF[fn], acc[fm][fn], 0, 0, 0);
    }

    // epilogue for this f-tile (registers only; next ft's first barrier protects bS)
    float psum[4] = {0.f,0.f,0.f,0.f};
    #pragma unroll
    for (int fn = 0; fn < 4; ++fn){
      int n = n0 + wc*64 + fn*16 + lm;
      float bias = b1[n];
      #pragma unroll
      for (int fm = 0; fm < 2; ++fm){
        int mb = m0 + wr*32 + fm*16 + g*4;
        #pragma unroll
        for (int r = 0; r < 4; ++r){
          float v = acc[fm][fn][r] + bias;
          v = 0.5f * v * (1.f + erff(v * 0.70710678118654752f));   // exact GELU
          H[(size_t)(mb + r)*FDIM + n] = f2bf(v);
          psum[fn] += v*v;
        }
      }
    }
    #pragma unroll
    for (int fn = 0; fn < 4; ++fn){
      float v = psum[fn];
      v += __shfl_xor(v, 16);
      v += __shfl_xor(v, 32);
      if (g == 0){
        atomicAdd(&grn[img*FDIM + n0 + wc*64 + fn*16 + lm], v);
      }
    }
  }
}

// ---------------- K7: GRN finalize -> S[n,f] = 1 + gamma[f]*nx
__global__ __launch_bounds__(256) void k_grn(const float* __restrict__ grn,
                                             const float* __restrict__ gamma,
                                             float* __restrict__ S){
  int n = blockIdx.x;
  const float* g = grn + n*FDIM;
  __shared__ float red[256];
  float p = 0.f;
  for (int f = threadIdx.x; f < FDIM; f += 256) p += sqrtf(g[f]);
  red[threadIdx.x] = p;
  __syncthreads();
  for (int s = 128; s > 0; s >>= 1){
    if (threadIdx.x < s) red[threadIdx.x] += red[threadIdx.x + s];
    __syncthreads();
  }
  float mean = red[0] * (1.f/FDIM);
  float inv = 1.f/(mean + 1e-6f);
  for (int f = threadIdx.x; f < FDIM; f += 256){
    float nx = sqrtf(g[f]) * inv;
    S[n*FDIM + f] = 1.f + gamma[f]*nx;
  }
}

// ---------------- K9: GEMM2 with prefetch: out[c,pix] = W2T·(H∘S) + c2 + x
__global__ __launch_bounds__(256) void k_gemm2(const unsigned short* __restrict__ W2T, // 384 x 1536
                                               const unsigned short* __restrict__ H,   // M x 1536
                                               const float* __restrict__ S,            // 8 x 1536
                                               const float* __restrict__ c2,
                                               const float* __restrict__ xg,
                                               float* __restrict__ out){
  __shared__ __align__(16) unsigned short aS[128*40];
  __shared__ __align__(16) unsigned short bS[128*40];
  int bid = blockIdx.x;
  int bm = bid % 3;            // channel tile
  int bn = bid / 3;            // pixel tile
  int c0 = bm*128, p0 = bn*128;
  int img = p0 >> 12;
  const float* Simg = S + img*FDIM;
  int tid = threadIdx.x;
  int lane = tid & 63, wid = tid >> 6;
  int wr = wid >> 1, wc = wid & 1;
  int lm = lane & 15, g = lane >> 4;
  int sr = tid & 127, sc = tid >> 7;
  f32x4 acc[4][4];
  #pragma unroll
  for (int i = 0; i < 4; ++i)
    #pragma unroll
    for (int j = 0; j < 4; ++j) acc[i][j] = (f32x4){0.f,0.f,0.f,0.f};

  // prologue loads (k0 = 0)
  short8 ra0, ra1, rh0, rh1;
  f32x4 rs0, rs1, rs2, rs3;
  {
    const unsigned short* ga = W2T + (size_t)(c0 + sr)*FDIM + sc*16;
    ra0 = *(const short8*)(ga); ra1 = *(const short8*)(ga + 8);
    const unsigned short* gb = H + (size_t)(p0 + sr)*FDIM + sc*16;
    rh0 = *(const short8*)(gb); rh1 = *(const short8*)(gb + 8);
    const float* sv = Simg + sc*16;
    rs0 = *(const f32x4*)(sv);      rs1 = *(const f32x4*)(sv + 4);
    rs2 = *(const f32x4*)(sv + 8);  rs3 = *(const f32x4*)(sv + 12);
  }

  #pragma unroll 1
  for (int ks = 0; ks < 48; ++ks){
    int k0 = ks*32;
    __syncthreads();
    *(short8*)&aS[sr*40 + sc*16]     = ra0;
    *(short8*)&aS[sr*40 + sc*16 + 8] = ra1;
    short8 o0, o1;
    float se[16];
    #pragma unroll
    for (int e = 0; e < 4; ++e){ se[e]=rs0[e]; se[4+e]=rs1[e]; se[8+e]=rs2[e]; se[12+e]=rs3[e]; }
    #pragma unroll
    for (int e = 0; e < 8; ++e){
      o0[e] = (short)f2bf(bf2f((unsigned short)rh0[e]) * se[e]);
      o1[e] = (short)f2bf(bf2f((unsigned short)rh1[e]) * se[e+8]);
    }
    *(short8*)&bS[sr*40 + sc*16]     = o0;
    *(short8*)&bS[sr*40 + sc*16 + 8] = o1;
    __syncthreads();
    // issue next-step loads; latency hides under ds_read + MFMA
    if (ks + 1 < 48){
      int nk = k0 + 32;
      const unsigned short* ga = W2T + (size_t)(c0 + sr)*FDIM + nk + sc*16;
      ra0 = *(const short8*)(ga); ra1 = *(const short8*)(ga + 8);
      const unsigned short* gb = H + (size_t)(p0 + sr)*FDIM + nk + sc*16;
      rh0 = *(const short8*)(gb); rh1 = *(const short8*)(gb + 8);
      const float* sv = Simg + nk + sc*16;
      rs0 = *(const f32x4*)(sv);      rs1 = *(const f32x4*)(sv + 4);
      rs2 = *(const f32x4*)(sv + 8);  rs3 = *(const f32x4*)(sv + 12);
    }
    bf16x8 aF[4], bF[4];
    #pragma unroll
    for (int fm = 0; fm < 4; ++fm) aF[fm] = *(const bf16x8*)&aS[(wr*64 + fm*16 + lm)*40 + g*8];
    #pragma unroll
    for (int fn = 0; fn < 4; ++fn) bF[fn] = *(const bf16x8*)&bS[(wc*64 + fn*16 + lm)*40 + g*8];
    #pragma unroll
    for (int fm = 0; fm < 4; ++fm)
      #pragma unroll
      for (int fn = 0; fn < 4; ++fn)
        acc[fm][fn] = __builtin_amdgcn_mfma_f32_16x16x32_bf16(aF[fm], bF[fn], acc[fm][fn], 0, 0, 0);
  }

  int sp0 = p0 & 4095;
  #pragma unroll
  for (int fn = 0; fn < 4; ++fn){
    int pixoff = sp0 + wc*64 + fn*16 + lm;
    #pragma unroll
    for (int fm = 0; fm < 4; ++fm){
      #pragma unroll
      for (int r = 0; r < 4; ++r){
        int c = c0 + wr*64 + fm*16 + g*4 + r;
        size_t addr = ((size_t)img*CDIM + c)*HW + pixoff;
        out[addr] = acc[fm][fn][r] + c2[c] + xg[addr];
      }
    }
  }
}

extern "C" void kernel_launch(void* const* d_in, const int* in_sizes, int n_in,
                              void* d_out, int out_size, void* d_ws, size_t ws_size,
                              hipStream_t stream) {
  const float* x    = (const float*)d_in[0];
  const float* wc   = (const float*)d_in[1];
  const float* kpe  = (const float*)d_in[2];
  const float* lnw  = (const float*)d_in[3];
  const float* lnb  = (const float*)d_in[4];
  const float* w1   = (const float*)d_in[5];
  const float* b1   = (const float*)d_in[6];
  const float* gam  = (const float*)d_in[7];
  const float* beta = (const float*)d_in[8];
  const float* w2   = (const float*)d_in[9];
  const float* b2   = (const float*)d_in[10];
  float* out = (float*)d_out;

  char* ws = (char*)d_ws;
  size_t o = 0;
  auto take = [&](size_t bytes)->char*{
    char* p = ws + o;
    o = (o + bytes + 511) & ~(size_t)511;
    return p;
  };
  // y (conv output) aliases d_out: fully consumed by k_ln before k_gemm2 writes.
  float*          y     = out;
  float*          wfull = (float*)take((size_t)CDIM*2601*4);
  unsigned short* yn    = (unsigned short*)take((size_t)NPIX*CDIM*2);
  unsigned short* H     = (unsigned short*)take((size_t)NPIX*FDIM*2);
  unsigned short* w1T   = (unsigned short*)take((size_t)CDIM*FDIM*2);
  unsigned short* w2T   = (unsigned short*)take((size_t)CDIM*FDIM*2);
  float*          grn   = (float*)take(8*FDIM*4);
  float*          S     = (float*)take(8*FDIM*4);
  float*          c2    = (float*)take(CDIM*4);
  if (o > ws_size) return;

  k_build_w<<<CDIM, 256, 0, stream>>>(wc, kpe, wfull);
  k_conv_mfma<<<3072, 256, 0, stream>>>(x, wfull, y);
  k_ln<<<NPIX/64, 256, 0, stream>>>(y, lnw, lnb, yn);
  k_wt<<<(CDIM/64)*(FDIM/64), 256, 0, stream>>>(w1, w1T, CDIM, FDIM);   // w1T[f][c]
  k_wt<<<(FDIM/64)*(CDIM/64), 256, 0, stream>>>(w2, w2T, FDIM, CDIM);   // w2T[c][f]
  k_c2<<<CDIM, 256, 0, stream>>>(w2, beta, b2, c2);
  hipMemsetAsync(grn, 0, 8*FDIM*4, stream);
  k_gemm1p<<<NPIX/64, 256, 0, stream>>>(yn, w1T, b1, H, grn);
  k_grn<<<8, 256, 0, stream>>>(grn, gam, S);
  k_gemm2<<<3*(NPIX/128), 256, 0, stream>>>(w2T, H, S, c2, x, out);
}

// Round 10
// 401.123 us; speedup vs baseline: 2.5858x; 1.1718x over previous
//
#include <hip/hip_runtime.h>

#define CDIM 384
#define FDIM 1536
#define KK 51
#define RAD 25
#define NPIX 32768     // B*H*W
#define HW 4096        // 64*64

#define CSTR 136       // shifted-copy stride (elements)
#define OSTR 68        // out accumulator row stride (f32 words)

typedef float  f32x4  __attribute__((ext_vector_type(4)));
typedef short  short8 __attribute__((ext_vector_type(8)));
typedef __bf16 bf16x8 __attribute__((ext_vector_type(8)));
typedef unsigned short us4 __attribute__((ext_vector_type(4)));

// per-axis peripheral index: coords {0,1,2,4,8,16,25}, signed list P=13
__device__ __constant__ int AXIS[51] = {
  0,
  1,1,1,1,1,1,1,1,1,
  2,2,2,2,2,2,2,2,
  3,3,3,3,
  4,4,
  5,
  6,
  7,
  8,8,
  9,9,9,9,
  10,10,10,10,10,10,10,10,
  11,11,11,11,11,11,11,11,11,
  12
};

__device__ __forceinline__ unsigned short bf16_rn(float x){
  union { float f; unsigned u; } v; v.f = x;
  unsigned r = v.u + 0x7FFFu + ((v.u >> 16) & 1u);
  return (unsigned short)(r >> 16);
}
__device__ __forceinline__ unsigned short f2bf(float x){
  __bf16 h = (__bf16)x;
  return __builtin_bit_cast(unsigned short, h);
}
__device__ __forceinline__ float bf2f(unsigned short h){
  union { unsigned u; float f; } v; v.u = ((unsigned)h) << 16; return v.f;
}

// ---------------- K-PREP: one launch for all small prep work.
// blocks [0,384): build wfull   [384,528): w1->w1T   [528,672): w2->w2T
// blocks [672,1056): c2         [1056]: zero grn
__global__ __launch_bounds__(256) void k_prep(const float* __restrict__ wc,
                                              const float* __restrict__ kpe,
                                              float* __restrict__ wfull,
                                              const float* __restrict__ w1,
                                              unsigned short* __restrict__ w1T,
                                              const float* __restrict__ w2,
                                              unsigned short* __restrict__ w2T,
                                              const float* __restrict__ beta,
                                              const float* __restrict__ b2,
                                              float* __restrict__ c2,
                                              float* __restrict__ grn){
  __shared__ float tile[64][65];
  __shared__ float red[256];
  int bid = blockIdx.x;
  int tid = threadIdx.x;
  if (bid < 384){
    int c = bid;
    const float* wcc = wc + c*169;
    float* wo = wfull + (size_t)c*2601;
    for (int idx = tid; idx < 2601; idx += 256){
      int i = idx / 51, j = idx - i*51;
      wo[idx] = wcc[AXIS[i]*13 + AXIS[j]] + kpe[idx];
    }
  } else if (bid < 1056 - 384){  // [384,672): transposes
    const float* src; unsigned short* dst; int R, C, t;
    if (bid < 528){ src = w1; dst = w1T; R = CDIM; C = FDIM; t = bid - 384; }
    else          { src = w2; dst = w2T; R = FDIM; C = CDIM; t = bid - 528; }
    int nct = C >> 6;
    int tc = t % nct, tr = t / nct;
    int r0 = tr*64, c0 = tc*64;
    int lane = tid & 63, q = tid >> 6;
    #pragma unroll
    for (int it = 0; it < 16; ++it){
      int r = it*4 + q;
      tile[r][lane] = src[(size_t)(r0 + r)*C + c0 + lane];
    }
    __syncthreads();
    #pragma unroll
    for (int it = 0; it < 16; ++it){
      int c = it*4 + q;
      dst[(size_t)(c0 + c)*R + r0 + lane] = f2bf(tile[lane][c]);
    }
  } else if (bid < 1056){
    int c = bid - 672;
    float s = 0.f;
    for (int f = tid; f < FDIM; f += 256) s += beta[f] * w2[(size_t)f*CDIM + c];
    red[tid] = s;
    __syncthreads();
    for (int t = 128; t > 0; t >>= 1){
      if (tid < t) red[tid] += red[tid + t];
      __syncthreads();
    }
    if (tid == 0) c2[c] = red[0] + b2[c];
  } else {
    for (int i = tid; i < 8*FDIM; i += 256) grn[i] = 0.f;
  }
}

// ---------------- K1: depthwise conv 51x51 via MFMA row-Toeplitz scatter,
// 4-row alignment-class batching + async-STAGE split. One block = one (b,c) image.
// (identical to round-8 version incl. bf16_rn staging — native-cast variant regressed)
__global__ __launch_bounds__(256) void k_conv_mfma(const float* __restrict__ x,
                                                   const float* __restrict__ wfull,
                                                   float* __restrict__ y){
  __shared__ __align__(16) float outb[64*OSTR];              // 17408 B accumulator
  __shared__ __align__(16) unsigned short bufs[2][4][1088];  // 17408 B row copies
  int img = blockIdx.x;                 // b*384 + c
  int ch  = img % CDIM;
  const float* xim = x + (size_t)img*HW;
  const float* wch = wfull + (size_t)ch*2601;
  int tid = threadIdx.x;
  int lane = tid & 63, wid = tid >> 6;  // wid = q-tile
  int li = lane & 15, g = lane >> 4;
  int t0 = (lane & 31) << 2;            // us4 position within a copy
  int c0 = lane >> 5;                   // base copy index (it adds 2 per step)

  for (int i = tid; i < 1088; i += 256)
    *(f32x4*)&outb[i*4] = (f32x4){0.f,0.f,0.f,0.f};

  bf16x8 Bf[4][2];
  #pragma unroll
  for (int nt = 0; nt < 4; ++nt){
    int i = nt*16 + li;
    #pragma unroll
    for (int kt = 0; kt < 2; ++kt){
      union { bf16x8 v; unsigned short u[8]; } tmp;
      #pragma unroll
      for (int e = 0; e < 8; ++e){
        int j = kt*32 + g*8 + e;
        float v = (i < 51 && j < 51) ? wch[i*51 + j] : 0.f;
        tmp.u[e] = bf16_rn(v);
      }
      Bf[nt][kt] = tmp.v;
    }
  }

  {
    const float* xr = xim + (16*wid)*64;
    #pragma unroll
    for (int it = 0; it < 4; ++it){
      int c = c0 + 2*it;
      us4 o;
      #pragma unroll
      for (int e = 0; e < 4; ++e){
        int xi = t0 + e + c - 25;
        float v = (xi >= 0 && xi < 64) ? xr[xi] : 0.f;
        o[e] = bf16_rn(v);
      }
      *(us4*)&bufs[0][wid][c*CSTR + t0] = o;
    }
  }
  __syncthreads();

  #pragma unroll 1
  for (int ph = 0; ph < 16; ++ph){
    float pf[16];
    if (ph + 1 < 16){
      const float* xr = xim + (ph + 1 + 16*wid)*64;
      #pragma unroll
      for (int it = 0; it < 4; ++it){
        int c = c0 + 2*it;
        #pragma unroll
        for (int e = 0; e < 4; ++e){
          int xi = t0 + e + c - 25;
          int xc = min(max(xi, 0), 63);
          pf[it*4 + e] = xr[xc];
        }
      }
    }

    bf16x8 Af[4][2];
    #pragma unroll
    for (int s = 0; s < 4; ++s){
      const unsigned short* bb = &bufs[ph & 1][s][0];
      #pragma unroll
      for (int kt = 0; kt < 2; ++kt){
        int u0 = wid*16 + kt*32 + g*8 + li;
        int c  = li & 7;
        Af[s][kt] = *(const bf16x8*)&bb[c*CSTR + (u0 - c)];
      }
    }

    #pragma unroll
    for (int dd = 0; dd < 6; ++dd){
      int d = dd - 2;
      int pmax = ph + 25 + 16*d;
      if (pmax < 0 || pmax > 78) continue;
      f32x4 V = {0.f,0.f,0.f,0.f};
      #pragma unroll
      for (int s = 0; s < 4; ++s){
        int nt = s - d;
        if (nt < 0 || nt > 3) continue;
        V = __builtin_amdgcn_mfma_f32_16x16x32_bf16(Af[s][0], Bf[nt][0], V, 0, 0, 0);
        V = __builtin_amdgcn_mfma_f32_16x16x32_bf16(Af[s][1], Bf[nt][1], V, 0, 0, 0);
      }
      int p = pmax - li;
      if (p >= 0 && p < 64){
        float* oa = &outb[p*OSTR + wid*16 + g*4];
        f32x4 old = *(const f32x4*)oa;
        *(f32x4*)oa = old + V;
      }
    }

    if (ph + 1 < 16){
      unsigned short* dst = &bufs[(ph + 1) & 1][wid][0];
      #pragma unroll
      for (int it = 0; it < 4; ++it){
        int c = c0 + 2*it;
        us4 o;
        #pragma unroll
        for (int e = 0; e < 4; ++e){
          int xi = t0 + e + c - 25;
          float v = (xi >= 0 && xi < 64) ? pf[it*4 + e] : 0.f;
          o[e] = bf16_rn(v);
        }
        *(us4*)&dst[c*CSTR + t0] = o;
      }
    }
    __syncthreads();
  }

  float* yo = y + (size_t)img*HW;
  #pragma unroll
  for (int k = 0; k < 4; ++k){
    int pix = k*1024 + tid*4;
    int p = pix >> 6, q = pix & 63;
    *(f32x4*)(yo + pix) = *(const f32x4*)&outb[p*OSTR + q];
  }
}

// ---------------- K2: LayerNorm (NCHW f32 -> NHWC bf16). 512 blocks x 64 pixels.
__global__ __launch_bounds__(256) void k_ln(const float* __restrict__ y,
                                            const float* __restrict__ lnw,
                                            const float* __restrict__ lnb,
                                            unsigned short* __restrict__ yn){
  __shared__ float sred[2][4][64];
  __shared__ unsigned short tile[384*66];   // [c][pixel] padded stride 66
  int tid = threadIdx.x, lane = tid & 63, w = tid >> 6;
  int pg0 = blockIdx.x * 64;
  int b = pg0 >> 12, sp0 = pg0 & 4095;
  const float* yb = y + (size_t)b*CDIM*HW + sp0 + lane;  // lane = pixel
  int cbase = w * 96;
  float sum = 0.f, sq = 0.f;
  for (int cc = 0; cc < 96; ++cc){
    float v = yb[(size_t)(cbase + cc)*HW];
    sum += v; sq += v*v;
  }
  sred[0][w][lane] = sum; sred[1][w][lane] = sq;
  __syncthreads();
  float ts = 0.f, tq = 0.f;
  #pragma unroll
  for (int u = 0; u < 4; ++u){ ts += sred[0][u][lane]; tq += sred[1][u][lane]; }
  float mu   = ts * (1.f/CDIM);
  float var  = tq * (1.f/CDIM) - mu*mu;
  float rstd = rsqrtf(var + 1e-6f);
  for (int cc = 0; cc < 96; ++cc){
    int c = cbase + cc;
    float v = (yb[(size_t)c*HW] - mu) * rstd * lnw[c] + lnb[c];
    tile[c*66 + lane] = f2bf(v);
  }
  __syncthreads();
  for (int pp = 0; pp < 16; ++pp){
    int p = w*16 + pp;
    size_t orow = (size_t)(pg0 + p)*CDIM;
    #pragma unroll
    for (int chk = 0; chk < 6; ++chk){
      yn[orow + chk*64 + lane] = tile[(chk*64 + lane)*66 + p];
    }
  }
}

// ---------------- K6: GEMM1 persistent-A, single-barrier double-buffered B.
__global__ __launch_bounds__(256) void k_gemm1p(const unsigned short* __restrict__ A,   // yn M x 384
                                                const unsigned short* __restrict__ BT,  // w1T 1536 x 384
                                                const float* __restrict__ b1,
                                                unsigned short* __restrict__ H,         // M x 1536
                                                float* __restrict__ grn){               // 8 x 1536
  __shared__ __align__(16) unsigned short pan[64*392];     // 49.1 KB A panel
  __shared__ __align__(16) unsigned short bS[2][128*40];   // 2 x 10.25 KB B tiles
  int m0 = blockIdx.x * 64;
  int img = m0 >> 12;
  int tid = threadIdx.x;
  int lane = tid & 63, wid = tid >> 6;
  int wr = wid >> 1, wc = wid & 1;     // wave tile: 32 pixels x 64 f
  int lm = lane & 15, g = lane >> 4;
  int sr = tid & 127, sc = tid >> 7;   // B staging coords

  // stage A panel once
  #pragma unroll
  for (int t = 0; t < 12; ++t){
    int idx = tid + 256*t;             // 0..3071 = 64*48
    int row = idx / 48, ch = idx - row*48;
    *(short8*)&pan[row*392 + ch*8] = *(const short8*)(A + (size_t)(m0 + row)*CDIM + ch*8);
  }

  // prologue: step0 -> bS[0]; rn = step1; (pft,pk) = step2
  {
    const unsigned short* gb = BT + (size_t)sr*CDIM + sc*16;
    *(short8*)&bS[0][sr*40 + sc*16]     = *(const short8*)(gb);
    *(short8*)&bS[0][sr*40 + sc*16 + 8] = *(const short8*)(gb + 8);
  }
  short8 rn0, rn1;
  {
    const unsigned short* gb = BT + (size_t)sr*CDIM + 32 + sc*16;
    rn0 = *(const short8*)(gb);
    rn1 = *(const short8*)(gb + 8);
  }
  int pft = 0, pk = 64;
  int par = 0;

  #pragma unroll 1
  for (int ft = 0; ft < 12; ++ft){
    f32x4 acc[2][4];
    #pragma unroll
    for (int i = 0; i < 2; ++i)
      #pragma unroll
      for (int j = 0; j < 4; ++j) acc[i][j] = (f32x4){0.f,0.f,0.f,0.f};

    #pragma unroll 1
    for (int ks = 0; ks < 12; ++ks){
      int k0 = ks*32;
      __syncthreads();                 // separates reads@prev-iter from writes@this-iter
      if (!(ft == 11 && ks == 11)){
        *(short8*)&bS[par^1][sr*40 + sc*16]     = rn0;
        *(short8*)&bS[par^1][sr*40 + sc*16 + 8] = rn1;
      }
      if (!(ft == 11 && ks >= 10)){    // load step+2
        const unsigned short* gb = BT + (size_t)(pft*128 + sr)*CDIM + pk + sc*16;
        rn0 = *(const short8*)(gb);
        rn1 = *(const short8*)(gb + 8);
        pk += 32; if (pk == CDIM){ pk = 0; ++pft; }
      }
      bf16x8 aF[2], bF[4];
      #pragma unroll
      for (int fm = 0; fm < 2; ++fm) aF[fm] = *(const bf16x8*)&pan[(wr*32 + fm*16 + lm)*392 + k0 + g*8];
      #pragma unroll
      for (int fn = 0; fn < 4; ++fn) bF[fn] = *(const bf16x8*)&bS[par][(wc*64 + fn*16 + lm)*40 + g*8];
      #pragma unroll
      for (int fm = 0; fm < 2; ++fm)
        #pragma unroll
        for (int fn = 0; fn < 4; ++fn)
          acc[fm][fn] = __builtin_amdgcn_mfma_f32_16x16x32_bf16(aF[fm], bF[fn], acc[fm][fn], 0, 0, 0);
      par ^= 1;
    }

    int n0 = ft*128;
    float psum[4] = {0.f,0.f,0.f,0.f};
    #pragma unroll
    for (int fn = 0; fn < 4; ++fn){
      int n = n0 + wc*64 + fn*16 + lm;
      float bias = b1[n];
      #pragma unroll
      for (int fm = 0; fm < 2; ++fm){
        int mb = m0 + wr*32 + fm*16 + g*4;
        #pragma unroll
        for (int r = 0; r < 4; ++r){
          float v = acc[fm][fn][r] + bias;
          v = 0.5f * v * (1.f + erff(v * 0.70710678118654752f));   // exact GELU
          H[(size_t)(mb + r)*FDIM + n] = f2bf(v);
          psum[fn] += v*v;
        }
      }
    }
    #pragma unroll
    for (int fn = 0; fn < 4; ++fn){
      float v = psum[fn];
      v += __shfl_xor(v, 16);
      v += __shfl_xor(v, 32);
      if (g == 0){
        atomicAdd(&grn[img*FDIM + n0 + wc*64 + fn*16 + lm], v);
      }
    }
  }
}

// ---------------- K7: GRN finalize -> S[n,f] = 1 + gamma[f]*nx
__global__ __launch_bounds__(256) void k_grn(const float* __restrict__ grn,
                                             const float* __restrict__ gamma,
                                             float* __restrict__ S){
  int n = blockIdx.x;
  const float* g = grn + n*FDIM;
  __shared__ float red[256];
  float p = 0.f;
  for (int f = threadIdx.x; f < FDIM; f += 256) p += sqrtf(g[f]);
  red[threadIdx.x] = p;
  __syncthreads();
  for (int s = 128; s > 0; s >>= 1){
    if (threadIdx.x < s) red[threadIdx.x] += red[threadIdx.x + s];
    __syncthreads();
  }
  float mean = red[0] * (1.f/FDIM);
  float inv = 1.f/(mean + 1e-6f);
  for (int f = threadIdx.x; f < FDIM; f += 256){
    float nx = sqrtf(g[f]) * inv;
    S[n*FDIM + f] = 1.f + gamma[f]*nx;
  }
}

// ---------------- K9: GEMM2, single-barrier double-buffered A and B.
__global__ __launch_bounds__(256) void k_gemm2(const unsigned short* __restrict__ W2T, // 384 x 1536
                                               const unsigned short* __restrict__ H,   // M x 1536
                                               const float* __restrict__ S,            // 8 x 1536
                                               const float* __restrict__ c2,
                                               const float* __restrict__ xg,
                                               float* __restrict__ out){
  __shared__ __align__(16) unsigned short aS[2][128*40];
  __shared__ __align__(16) unsigned short bS[2][128*40];
  int bid = blockIdx.x;
  int bm = bid % 3;            // channel tile
  int bn = bid / 3;            // pixel tile
  int c0 = bm*128, p0 = bn*128;
  int img = p0 >> 12;
  const float* Simg = S + img*FDIM;
  int tid = threadIdx.x;
  int lane = tid & 63, wid = tid >> 6;
  int wr = wid >> 1, wc = wid & 1;
  int lm = lane & 15, g = lane >> 4;
  int sr = tid & 127, sc = tid >> 7;
  f32x4 acc[4][4];
  #pragma unroll
  for (int i = 0; i < 4; ++i)
    #pragma unroll
    for (int j = 0; j < 4; ++j) acc[i][j] = (f32x4){0.f,0.f,0.f,0.f};

  // prologue: step0 directly to LDS; step1 to regs
  {
    const unsigned short* ga = W2T + (size_t)(c0 + sr)*FDIM + sc*16;
    *(short8*)&aS[0][sr*40 + sc*16]     = *(const short8*)(ga);
    *(short8*)&aS[0][sr*40 + sc*16 + 8] = *(const short8*)(ga + 8);
    const unsigned short* gb = H + (size_t)(p0 + sr)*FDIM + sc*16;
    short8 h0 = *(const short8*)(gb);
    short8 h1 = *(const short8*)(gb + 8);
    const float* sv = Simg + sc*16;
    short8 o0, o1;
    #pragma unroll
    for (int e = 0; e < 8; ++e){
      o0[e] = (short)f2bf(bf2f((unsigned short)h0[e]) * sv[e]);
      o1[e] = (short)f2bf(bf2f((unsigned short)h1[e]) * sv[e+8]);
    }
    *(short8*)&bS[0][sr*40 + sc*16]     = o0;
    *(short8*)&bS[0][sr*40 + sc*16 + 8] = o1;
  }
  short8 ra0, ra1, rh0, rh1;
  f32x4 rs0, rs1, rs2, rs3;
  {
    const unsigned short* ga = W2T + (size_t)(c0 + sr)*FDIM + 32 + sc*16;
    ra0 = *(const short8*)(ga); ra1 = *(const short8*)(ga + 8);
    const unsigned short* gb = H + (size_t)(p0 + sr)*FDIM + 32 + sc*16;
    rh0 = *(const short8*)(gb); rh1 = *(const short8*)(gb + 8);
    const float* sv = Simg + 32 + sc*16;
    rs0 = *(const f32x4*)(sv);      rs1 = *(const f32x4*)(sv + 4);
    rs2 = *(const f32x4*)(sv + 8);  rs3 = *(const f32x4*)(sv + 12);
  }
  int par = 0;

  #pragma unroll 1
  for (int ks = 0; ks < 48; ++ks){
    __syncthreads();
    if (ks + 1 < 48){
      *(short8*)&aS[par^1][sr*40 + sc*16]     = ra0;
      *(short8*)&aS[par^1][sr*40 + sc*16 + 8] = ra1;
      short8 o0, o1;
      float se[16];
      #pragma unroll
      for (int e = 0; e < 4; ++e){ se[e]=rs0[e]; se[4+e]=rs1[e]; se[8+e]=rs2[e]; se[12+e]=rs3[e]; }
      #pragma unroll
      for (int e = 0; e < 8; ++e){
        o0[e] = (short)f2bf(bf2f((unsigned short)rh0[e]) * se[e]);
        o1[e] = (short)f2bf(bf2f((unsigned short)rh1[e]) * se[e+8]);
      }
      *(short8*)&bS[par^1][sr*40 + sc*16]     = o0;
      *(short8*)&bS[par^1][sr*40 + sc*16 + 8] = o1;
    }
    if (ks + 2 < 48){
      int nk = (ks + 2)*32;
      const unsigned short* ga = W2T + (size_t)(c0 + sr)*FDIM + nk + sc*16;
      ra0 = *(const short8*)(ga); ra1 = *(const short8*)(ga + 8);
      const unsigned short* gb = H + (size_t)(p0 + sr)*FDIM + nk + sc*16;
      rh0 = *(const short8*)(gb); rh1 = *(const short8*)(gb + 8);
      const float* sv = Simg + nk + sc*16;
      rs0 = *(const f32x4*)(sv);      rs1 = *(const f32x4*)(sv + 4);
      rs2 = *(const f32x4*)(sv + 8);  rs3 = *(const f32x4*)(sv + 12);
    }
    bf16x8 aF[4], bF[4];
    #pragma unroll
    for (int fm = 0; fm < 4; ++fm) aF[fm] = *(const bf16x8*)&aS[par][(wr*64 + fm*16 + lm)*40 + g*8];
    #pragma unroll
    for (int fn = 0; fn < 4; ++fn) bF[fn] = *(const bf16x8*)&bS[par][(wc*64 + fn*16 + lm)*40 + g*8];
    #pragma unroll
    for (int fm = 0; fm < 4; ++fm)
      #pragma unroll
      for (int fn = 0; fn < 4; ++fn)
        acc[fm][fn] = __builtin_amdgcn_mfma_f32_16x16x32_bf16(aF[fm], bF[fn], acc[fm][fn], 0, 0, 0);
    par ^= 1;
  }

  int sp0 = p0 & 4095;
  #pragma unroll
  for (int fn = 0; fn < 4; ++fn){
    int pixoff = sp0 + wc*64 + fn*16 + lm;
    #pragma unroll
    for (int fm = 0; fm < 4; ++fm){
      #pragma unroll
      for (int r = 0; r < 4; ++r){
        int c = c0 + wr*64 + fm*16 + g*4 + r;
        size_t addr = ((size_t)img*CDIM + c)*HW + pixoff;
        out[addr] = acc[fm][fn][r] + c2[c] + xg[addr];
      }
    }
  }
}

extern "C" void kernel_launch(void* const* d_in, const int* in_sizes, int n_in,
                              void* d_out, int out_size, void* d_ws, size_t ws_size,
                              hipStream_t stream) {
  const float* x    = (const float*)d_in[0];
  const float* wc   = (const float*)d_in[1];
  const float* kpe  = (const float*)d_in[2];
  const float* lnw  = (const float*)d_in[3];
  const float* lnb  = (const float*)d_in[4];
  const float* w1   = (const float*)d_in[5];
  const float* b1   = (const float*)d_in[6];
  const float* gam  = (const float*)d_in[7];
  const float* beta = (const float*)d_in[8];
  const float* w2   = (const float*)d_in[9];
  const float* b2   = (const float*)d_in[10];
  float* out = (float*)d_out;

  char* ws = (char*)d_ws;
  size_t o = 0;
  auto take = [&](size_t bytes)->char*{
    char* p = ws + o;
    o = (o + bytes + 511) & ~(size_t)511;
    return p;
  };
  // y (conv output) aliases d_out: fully consumed by k_ln before k_gemm2 writes.
  float*          y     = out;
  float*          wfull = (float*)take((size_t)CDIM*2601*4);
  unsigned short* yn    = (unsigned short*)take((size_t)NPIX*CDIM*2);
  unsigned short* H     = (unsigned short*)take((size_t)NPIX*FDIM*2);
  unsigned short* w1T   = (unsigned short*)take((size_t)CDIM*FDIM*2);
  unsigned short* w2T   = (unsigned short*)take((size_t)CDIM*FDIM*2);
  float*          grn   = (float*)take(8*FDIM*4);
  float*          S     = (float*)take(8*FDIM*4);
  float*          c2    = (float*)take(CDIM*4);
  if (o > ws_size) return;

  k_prep<<<1057, 256, 0, stream>>>(wc, kpe, wfull, w1, w1T, w2, w2T, beta, b2, c2, grn);
  k_conv_mfma<<<3072, 256, 0, stream>>>(x, wfull, y);
  k_ln<<<NPIX/64, 256, 0, stream>>>(y, lnw, lnb, yn);
  k_gemm1p<<<NPIX/64, 256, 0, stream>>>(yn, w1T, b1, H, grn);
  k_grn<<<8, 256, 0, stream>>>(grn, gam, S);
  k_gemm2<<<3*(NPIX/128), 256, 0, stream>>>(w2T, H, S, c2, x, out);
}